// Round 5
// baseline (1606.511 us; speedup 1.0000x reference)
//
#include <hip/hip_runtime.h>

typedef unsigned short u16;
typedef __attribute__((ext_vector_type(8))) short bf16x8;
typedef __attribute__((ext_vector_type(4))) float f32x4;

#define MFMA16(a,b,c) __builtin_amdgcn_mfma_f32_16x16x32_bf16((a),(b),(c),0,0,0)

static __device__ __forceinline__ u16 f2bf(float x){
    unsigned int u = __float_as_uint(x);
    u += 0x7FFFu + ((u >> 16) & 1u);
    return (u16)(u >> 16);
}
static __device__ __forceinline__ float bf2f(short s){
    return __uint_as_float(((unsigned int)(u16)s) << 16);
}

static __device__ __forceinline__ bf16x8 load_bfrag(const float* __restrict__ W, int ldn, int n, int k0){
    bf16x8 r;
    #pragma unroll
    for (int j = 0; j < 8; ++j) r[j] = (short)f2bf(W[(k0 + j) * ldn + n]);
    return r;
}

// ---------------- encoder: h = relu(x@W1+b1)@W2 + b2 ; emit h, U0, V0 --------
__global__ __launch_bounds__(256) void enc_kernel(
    const float* __restrict__ X, const float* __restrict__ W1, const float* __restrict__ B1,
    const float* __restrict__ W2, const float* __restrict__ B2,
    const float* __restrict__ cW1, const float* __restrict__ cB1,   // conv layer-0
    u16* __restrict__ hbf, u16* __restrict__ Ubf, u16* __restrict__ Vbf, int N)
{
    __shared__ u16 sHid[64 * 136];
    __shared__ u16 sH[64 * 72];
    const int tid = threadIdx.x;
    const int w = tid >> 6, l = tid & 63, l15 = l & 15, quad = l >> 4;

    bf16x8 bW[4][4];
    #pragma unroll
    for (int ks = 0; ks < 4; ++ks)
        #pragma unroll
        for (int f = 0; f < 4; ++f)
            bW[ks][f] = load_bfrag(W2, 64, f * 16 + l15, ks * 32 + quad * 8);
    float b2v[4];
    #pragma unroll
    for (int f = 0; f < 4; ++f) b2v[f] = B2[f * 16 + l15];

    const int nbase = blockIdx.x * 64 + w * 16;

    {
        int e = l >> 2;
        int node = nbase + e; if (node > N - 1) node = N - 1;
        float x0 = X[node * 3], x1 = X[node * 3 + 1], x2 = X[node * 3 + 2];
        int k0 = (l & 3) * 32;
        u16* dst = sHid + (w * 16 + e) * 136 + k0;
        #pragma unroll
        for (int j = 0; j < 32; ++j){
            int k = k0 + j;
            float hv = x0 * W1[k] + x1 * W1[128 + k] + x2 * W1[256 + k] + B1[k];
            dst[j] = f2bf(hv > 0.f ? hv : 0.f);
        }
    }

    f32x4 acc[4];
    #pragma unroll
    for (int f = 0; f < 4; ++f){ acc[f][0]=b2v[f]; acc[f][1]=b2v[f]; acc[f][2]=b2v[f]; acc[f][3]=b2v[f]; }
    #pragma unroll
    for (int ks = 0; ks < 4; ++ks){
        bf16x8 a = *(const bf16x8*)&sHid[(w * 16 + l15) * 136 + ks * 32 + quad * 8];
        #pragma unroll
        for (int f = 0; f < 4; ++f) acc[f] = MFMA16(a, bW[ks][f], acc[f]);
    }
    #pragma unroll
    for (int r = 0; r < 4; ++r){
        int node = nbase + quad * 4 + r;
        #pragma unroll
        for (int f = 0; f < 4; ++f){
            u16 hb = f2bf(acc[f][r]);
            sH[(w * 16 + quad * 4 + r) * 72 + f * 16 + l15] = hb;
            if (node < N) hbf[(size_t)node * 64 + f * 16 + l15] = hb;
        }
    }

    // U = h@cW1a + cB1 ; V = h@cW1b   (same-wave LDS write->read, no barrier)
    bf16x8 bA[2][4], bB[2][4];
    #pragma unroll
    for (int kk = 0; kk < 2; ++kk)
        #pragma unroll
        for (int f = 0; f < 4; ++f){
            int n = f * 16 + l15, k0 = kk * 32 + quad * 8;
            bA[kk][f] = load_bfrag(cW1,           64, n, k0);
            bB[kk][f] = load_bfrag(cW1 + 64 * 64, 64, n, k0);
        }
    float b1n[4];
    #pragma unroll
    for (int f = 0; f < 4; ++f) b1n[f] = cB1[f * 16 + l15];

    bf16x8 a0 = *(const bf16x8*)&sH[(w * 16 + l15) * 72 + quad * 8];
    bf16x8 a1 = *(const bf16x8*)&sH[(w * 16 + l15) * 72 + 32 + quad * 8];

    f32x4 ua[4], va[4];
    #pragma unroll
    for (int f = 0; f < 4; ++f){
        ua[f][0]=b1n[f]; ua[f][1]=b1n[f]; ua[f][2]=b1n[f]; ua[f][3]=b1n[f];
        va[f][0]=0.f; va[f][1]=0.f; va[f][2]=0.f; va[f][3]=0.f;
    }
    #pragma unroll
    for (int f = 0; f < 4; ++f){ ua[f] = MFMA16(a0, bA[0][f], ua[f]); va[f] = MFMA16(a0, bB[0][f], va[f]); }
    #pragma unroll
    for (int f = 0; f < 4; ++f){ ua[f] = MFMA16(a1, bA[1][f], ua[f]); va[f] = MFMA16(a1, bB[1][f], va[f]); }

    #pragma unroll
    for (int r = 0; r < 4; ++r){
        int node = nbase + quad * 4 + r;
        if (node < N){
            #pragma unroll
            for (int f = 0; f < 4; ++f){
                Ubf[(size_t)node * 64 + f * 16 + l15] = f2bf(ua[f][r]);
                Vbf[(size_t)node * 64 + f * 16 + l15] = f2bf(va[f][r]);
            }
        }
    }
}

// ---------------- bucket binning build (bucket = 64 dest rows) ---------------
// NB <= 1024 assumed (N <= 65536).

__global__ __launch_bounds__(256) void countB_kernel(const int* __restrict__ rows,
                                                     int* __restrict__ countsB, int E, int NB){
    __shared__ int c[1024];
    for (int i = threadIdx.x; i < NB; i += 256) c[i] = 0;
    __syncthreads();
    for (int i = blockIdx.x * 256 + threadIdx.x; i < E; i += gridDim.x * 256)
        atomicAdd(&c[rows[i] >> 6], 1);
    __syncthreads();
    for (int i = threadIdx.x; i < NB; i += 256){
        int v = c[i];
        if (v) atomicAdd(&countsB[i], v);
    }
}

__global__ __launch_bounds__(1024) void scanB_kernel(const int* __restrict__ countsB,
                                                     int* __restrict__ offsets,
                                                     int* __restrict__ cursorB, int NB){
    __shared__ int sc[1024];
    const int tid = threadIdx.x;
    int x = (tid < NB) ? countsB[tid] : 0;
    sc[tid] = x;
    __syncthreads();
    for (int d = 1; d < 1024; d <<= 1){
        int v = (tid >= d) ? sc[tid - d] : 0;
        __syncthreads();
        sc[tid] += v;
        __syncthreads();
    }
    int excl = sc[tid] - x;
    if (tid < NB){ offsets[tid] = excl; cursorB[tid] = excl; }
    if (tid == NB - 1) offsets[NB] = sc[tid];
}

#define CHUNK 8192

// chunk-local counting sort by bucket, then contiguous run writes per bucket
__global__ __launch_bounds__(1024) void binpack_kernel(
    const int* __restrict__ rows, const int* __restrict__ cols,
    const float* __restrict__ EF, int* __restrict__ cursorB,
    uint2* __restrict__ erec, int E)
{
    __shared__ u16 sRow[CHUNK];
    __shared__ u16 sPerm[CHUNK];
    __shared__ int cntA[1024], cntE[1024], cntC[1024], baseB[1024], sc[1024];
    const int tid = threadIdx.x;
    const int cbase = blockIdx.x * CHUNK;
    int C = E - cbase; if (C > CHUNK) C = CHUNK;
    if (C <= 0) return;

    cntA[tid] = 0;
    __syncthreads();
    for (int k = tid; k < C; k += 1024){
        int r = rows[cbase + k];
        sRow[k] = (u16)r;
        atomicAdd(&cntA[r >> 6], 1);
    }
    __syncthreads();
    sc[tid] = cntA[tid];
    __syncthreads();
    for (int d = 1; d < 1024; d <<= 1){
        int v = (tid >= d) ? sc[tid - d] : 0;
        __syncthreads();
        sc[tid] += v;
        __syncthreads();
    }
    int excl = sc[tid] - cntA[tid];
    cntE[tid] = excl;
    cntC[tid] = excl;
    if (cntA[tid] > 0) baseB[tid] = atomicAdd(&cursorB[tid], cntA[tid]);
    __syncthreads();
    for (int k = tid; k < C; k += 1024){
        int b = sRow[k] >> 6;
        int p = atomicAdd(&cntC[b], 1);
        sPerm[p] = (u16)k;
    }
    __syncthreads();
    for (int p = tid; p < C; p += 1024){
        int k = sPerm[p];
        int i = cbase + k;
        int r = sRow[k];
        int b = r >> 6;
        float2 ef = *(const float2*)&EF[2 * i];
        uint2 v;
        v.x = (unsigned)r | ((unsigned)cols[i] << 16);
        v.y = (unsigned)f2bf(ef.x) | ((unsigned)f2bf(ef.y) << 16);
        erec[baseB[b] + (p - cntE[b])] = v;
    }
}

// issue U/V gathers for a record (loads start here; waited at first use)
#define ISSUE_UV(recv, U0, U1, V0, V1) do {                                  \
    int rr_ = (int)((recv).x & 0xFFFFu); if (rr_ == 0xFFFF) rr_ = 0;         \
    int cc_ = (int)((recv).x >> 16);                                         \
    const u16* pu_ = Ubf + (size_t)rr_ * 64 + quad * 8;                      \
    const u16* pv_ = Vbf + (size_t)cc_ * 64 + quad * 8;                      \
    U0 = *(const bf16x8*)(pu_);                                              \
    U1 = *(const bf16x8*)(pu_ + 32);                                         \
    V0 = *(const bf16x8*)(pv_);                                              \
    V1 = *(const bf16x8*)(pv_ + 32);                                         \
} while (0)

// ------ message: one block per bucket; LDS tile aggregation; no gl atomics ---
__global__ __launch_bounds__(256, 3) void msg_kernel(
    const u16* __restrict__ Ubf, const u16* __restrict__ Vbf,
    const uint2* __restrict__ erec, const int* __restrict__ offsets,
    const float* __restrict__ W1,   // [130][64] of this layer (ef rows 128,129)
    const float* __restrict__ W2, const float* __restrict__ B2,
    float* __restrict__ agg, int N)
{
    __shared__ float aggT[64][68];
    __shared__ float sMsg[4][16 * 68];
    const int tid = threadIdx.x;
    const int w = tid >> 6, l = tid & 63, l15 = l & 15, quad = l >> 4;
    const int w16 = w * 16;

    bf16x8 bW2[2][4];
    #pragma unroll
    for (int kk = 0; kk < 2; ++kk)
        #pragma unroll
        for (int f = 0; f < 4; ++f)
            bW2[kk][f] = load_bfrag(W2, 64, f * 16 + l15, kk * 32 + quad * 8);
    float bias2[4];
    #pragma unroll
    for (int f = 0; f < 4; ++f) bias2[f] = B2[f * 16 + l15];

    const float* Wc0 = W1 + 128 * 64;
    const float* Wc1 = W1 + 129 * 64;
    float e0l[8], e0h[8], e1l[8], e1h[8];
    #pragma unroll
    for (int j = 0; j < 8; ++j){
        int kl = quad * 8 + j;
        e0l[j] = Wc0[kl];       e0h[j] = Wc0[32 + kl];
        e1l[j] = Wc1[kl];       e1h[j] = Wc1[32 + kl];
    }

    for (int i = tid; i < 64 * 68; i += 256) ((float*)aggT)[i] = 0.f;

    const int b = blockIdx.x;
    const int start = offsets[b], end = offsets[b + 1];
    const int nt = (end - start + 63) >> 6;
    float* myMsg = sMsg[w];
    __syncthreads();

    if (nt > 0){
        auto LOADREC = [&](int t) -> uint2 {
            int e = start + t * 64 + w16 + l15;
            if (e < end) return erec[e];
            uint2 s; s.x = 0x0000FFFFu; s.y = 0u; return s;
        };

        uint2 recA = LOADREC(0);
        uint2 recB = (nt > 1) ? LOADREC(1) : recA;
        bf16x8 u0, u1, v0, v1;
        ISSUE_UV(recA, u0, u1, v0, v1);

        for (int t = 0; t < nt; ++t){
            uint2 recC = LOADREC(t + 2 < nt ? t + 2 : nt - 1);
            bf16x8 nu0, nu1, nv0, nv1;
            ISSUE_UV(recB, nu0, nu1, nv0, nv1);     // next tile's gathers in flight

            int rn_raw = (int)(recA.x & 0xFFFFu);
            int lrow = (rn_raw == 0xFFFF) ? -1 : (rn_raw & 63);
            float ef0 = bf2f((short)(recA.y & 0xFFFFu));
            float ef1 = bf2f((short)(recA.y >> 16));

            float hA[8], hB[8];
            #pragma unroll
            for (int j = 0; j < 8; ++j){
                hA[j] = fmaf(ef1, e1l[j], ef0 * e0l[j]);
                hB[j] = fmaf(ef1, e1h[j], ef0 * e0h[j]);
            }

            bf16x8 a0, a1;
            #pragma unroll
            for (int j = 0; j < 8; ++j){
                float xl = hA[j] + bf2f(u0[j]) + bf2f(v0[j]);
                float xh = hB[j] + bf2f(u1[j]) + bf2f(v1[j]);
                a0[j] = (short)f2bf(xl > 0.f ? xl : 0.f);
                a1[j] = (short)f2bf(xh > 0.f ? xh : 0.f);
            }

            f32x4 m[4];
            #pragma unroll
            for (int f = 0; f < 4; ++f){ m[f][0]=bias2[f]; m[f][1]=bias2[f]; m[f][2]=bias2[f]; m[f][3]=bias2[f]; }
            #pragma unroll
            for (int f = 0; f < 4; ++f) m[f] = MFMA16(a0, bW2[0][f], m[f]);
            #pragma unroll
            for (int f = 0; f < 4; ++f) m[f] = MFMA16(a1, bW2[1][f], m[f]);

            // C-layout messages -> LDS so lane = feature
            #pragma unroll
            for (int f = 0; f < 4; ++f)
                #pragma unroll
                for (int r = 0; r < 4; ++r)
                    myMsg[(quad * 4 + r) * 68 + f * 16 + l15] = m[f][r];

            // LDS tile accumulation (wave-uniform row per j)
            #pragma unroll
            for (int j = 0; j < 16; ++j){
                int lr = __shfl(lrow, j);
                if (lr >= 0) atomicAdd(&aggT[lr][l], myMsg[j * 68 + l]);
            }

            recA = recB; recB = recC;
            u0 = nu0; u1 = nu1; v0 = nv0; v1 = nv1;
        }
    }

    __syncthreads();
    for (int i = tid; i < 4096; i += 256){
        int r = i >> 6, f = i & 63;
        int node = b * 64 + r;
        if (node < N) agg[(size_t)node * 64 + f] = aggT[r][f];
    }
}

// ------- update: h = relu(LN(agg + h@SW + SB)); emit U,V for next layer ------
__global__ __launch_bounds__(256) void update_kernel(
    u16* __restrict__ hbf, const float* __restrict__ agg,
    const float* __restrict__ SW, const float* __restrict__ SB,
    const float* __restrict__ LG, const float* __restrict__ LB,
    const float* __restrict__ cW1, const float* __restrict__ cB1,  // next layer (may be null)
    u16* __restrict__ Ubf, u16* __restrict__ Vbf, int N)
{
    __shared__ u16 sH[64 * 72];
    const int tid = threadIdx.x;
    const int w = tid >> 6, l = tid & 63, l15 = l & 15, quad = l >> 4;

    bf16x8 bW[2][4];
    #pragma unroll
    for (int kk = 0; kk < 2; ++kk)
        #pragma unroll
        for (int f = 0; f < 4; ++f)
            bW[kk][f] = load_bfrag(SW, 64, f * 16 + l15, kk * 32 + quad * 8);
    float sb[4], lg[4], lb[4];
    #pragma unroll
    for (int f = 0; f < 4; ++f){
        int n = f * 16 + l15;
        sb[f] = SB[n]; lg[f] = LG[n]; lb[f] = LB[n];
    }

    const int nbase = blockIdx.x * 64 + w * 16;
    int na = nbase + l15; if (na > N - 1) na = N - 1;
    const u16* pa = hbf + (size_t)na * 64 + quad * 8;
    bf16x8 h0 = *(const bf16x8*)pa;
    bf16x8 h1 = *(const bf16x8*)(pa + 32);

    f32x4 acc[4] = {};
    #pragma unroll
    for (int f = 0; f < 4; ++f) acc[f] = MFMA16(h0, bW[0][f], acc[f]);
    #pragma unroll
    for (int f = 0; f < 4; ++f) acc[f] = MFMA16(h1, bW[1][f], acc[f]);

    float vals[4][4];
    #pragma unroll
    for (int r = 0; r < 4; ++r){
        int node = nbase + quad * 4 + r; if (node > N - 1) node = N - 1;
        #pragma unroll
        for (int f = 0; f < 4; ++f)
            vals[f][r] = acc[f][r] + sb[f] + agg[(size_t)node * 64 + f * 16 + l15];
    }

    #pragma unroll
    for (int r = 0; r < 4; ++r){
        float s  = vals[0][r] + vals[1][r] + vals[2][r] + vals[3][r];
        float sq = vals[0][r]*vals[0][r] + vals[1][r]*vals[1][r]
                 + vals[2][r]*vals[2][r] + vals[3][r]*vals[3][r];
        #pragma unroll
        for (int msk = 1; msk < 16; msk <<= 1){
            s  += __shfl_xor(s,  msk);
            sq += __shfl_xor(sq, msk);
        }
        float mean = s * (1.f / 64.f);
        float var  = sq * (1.f / 64.f) - mean * mean;
        float rstd = rsqrtf(var + 1e-5f);
        int node = nbase + quad * 4 + r;
        #pragma unroll
        for (int f = 0; f < 4; ++f){
            float hv = (vals[f][r] - mean) * rstd * lg[f] + lb[f];
            hv = hv > 0.f ? hv : 0.f;
            u16 hb = f2bf(hv);
            sH[(w * 16 + quad * 4 + r) * 72 + f * 16 + l15] = hb;
            if (node < N) hbf[(size_t)node * 64 + f * 16 + l15] = hb;
        }
    }

    if (cW1){
        bf16x8 bA[2][4], bB[2][4];
        #pragma unroll
        for (int kk = 0; kk < 2; ++kk)
            #pragma unroll
            for (int f = 0; f < 4; ++f){
                int n = f * 16 + l15, k0 = kk * 32 + quad * 8;
                bA[kk][f] = load_bfrag(cW1,           64, n, k0);
                bB[kk][f] = load_bfrag(cW1 + 64 * 64, 64, n, k0);
            }
        float b1n[4];
        #pragma unroll
        for (int f = 0; f < 4; ++f) b1n[f] = cB1[f * 16 + l15];

        bf16x8 a0 = *(const bf16x8*)&sH[(w * 16 + l15) * 72 + quad * 8];
        bf16x8 a1 = *(const bf16x8*)&sH[(w * 16 + l15) * 72 + 32 + quad * 8];

        f32x4 ua[4], va[4];
        #pragma unroll
        for (int f = 0; f < 4; ++f){
            ua[f][0]=b1n[f]; ua[f][1]=b1n[f]; ua[f][2]=b1n[f]; ua[f][3]=b1n[f];
            va[f][0]=0.f; va[f][1]=0.f; va[f][2]=0.f; va[f][3]=0.f;
        }
        #pragma unroll
        for (int f = 0; f < 4; ++f){ ua[f] = MFMA16(a0, bA[0][f], ua[f]); va[f] = MFMA16(a0, bB[0][f], va[f]); }
        #pragma unroll
        for (int f = 0; f < 4; ++f){ ua[f] = MFMA16(a1, bA[1][f], ua[f]); va[f] = MFMA16(a1, bB[1][f], va[f]); }

        #pragma unroll
        for (int r = 0; r < 4; ++r){
            int node = nbase + quad * 4 + r;
            if (node < N){
                #pragma unroll
                for (int f = 0; f < 4; ++f){
                    Ubf[(size_t)node * 64 + f * 16 + l15] = f2bf(ua[f][r]);
                    Vbf[(size_t)node * 64 + f * 16 + l15] = f2bf(va[f][r]);
                }
            }
        }
    }
}

// ---------------- head: out = relu(h@W1+b1)@W2 + b2  [N][8] f32 --------------
__global__ __launch_bounds__(256) void head_kernel(
    const u16* __restrict__ hbf,
    const float* __restrict__ W1, const float* __restrict__ B1,
    const float* __restrict__ W2, const float* __restrict__ B2,
    float* __restrict__ out, int N)
{
    __shared__ u16 sT[64 * 72];
    const int tid = threadIdx.x;
    const int w = tid >> 6, l = tid & 63, l15 = l & 15, quad = l >> 4;

    bf16x8 bW1[2][4];
    #pragma unroll
    for (int kk = 0; kk < 2; ++kk)
        #pragma unroll
        for (int f = 0; f < 4; ++f)
            bW1[kk][f] = load_bfrag(W1, 64, f * 16 + l15, kk * 32 + quad * 8);
    float b1v[4];
    #pragma unroll
    for (int f = 0; f < 4; ++f) b1v[f] = B1[f * 16 + l15];

    bf16x8 bW2[2];
    #pragma unroll
    for (int kk = 0; kk < 2; ++kk)
        #pragma unroll
        for (int j = 0; j < 8; ++j){
            int k = kk * 32 + quad * 8 + j;
            bW2[kk][j] = (l15 < 8) ? (short)f2bf(W2[k * 8 + l15]) : (short)0;
        }
    float b2v = (l15 < 8) ? B2[l15] : 0.f;

    const int nbase = blockIdx.x * 64 + w * 16;
    int na = nbase + l15; if (na > N - 1) na = N - 1;
    const u16* pa = hbf + (size_t)na * 64 + quad * 8;
    bf16x8 a0 = *(const bf16x8*)pa;
    bf16x8 a1 = *(const bf16x8*)(pa + 32);

    f32x4 acc[4];
    #pragma unroll
    for (int f = 0; f < 4; ++f){ acc[f][0]=b1v[f]; acc[f][1]=b1v[f]; acc[f][2]=b1v[f]; acc[f][3]=b1v[f]; }
    #pragma unroll
    for (int f = 0; f < 4; ++f) acc[f] = MFMA16(a0, bW1[0][f], acc[f]);
    #pragma unroll
    for (int f = 0; f < 4; ++f) acc[f] = MFMA16(a1, bW1[1][f], acc[f]);

    u16* myT = sT + (w * 16) * 72;
    #pragma unroll
    for (int f = 0; f < 4; ++f)
        #pragma unroll
        for (int r = 0; r < 4; ++r){
            float v = acc[f][r] > 0.f ? acc[f][r] : 0.f;
            myT[(quad * 4 + r) * 72 + f * 16 + l15] = f2bf(v);
        }

    f32x4 o = { b2v, b2v, b2v, b2v };
    #pragma unroll
    for (int kk = 0; kk < 2; ++kk){
        bf16x8 a = *(const bf16x8*)&myT[l15 * 72 + kk * 32 + quad * 8];
        o = MFMA16(a, bW2[kk], o);
    }
    #pragma unroll
    for (int r = 0; r < 4; ++r){
        int node = nbase + quad * 4 + r;
        if (node < N && l15 < 8)
            out[(size_t)node * 8 + l15] = o[r];
    }
}

extern "C" void kernel_launch(void* const* d_in, const int* in_sizes, int n_in,
                              void* d_out, int out_size, void* d_ws, size_t ws_size,
                              hipStream_t stream)
{
    const float* X      = (const float*)d_in[0];
    const int*   EI     = (const int*)d_in[1];
    const float* EF     = (const float*)d_in[2];
    const float* encW1  = (const float*)d_in[4];
    const float* encB1  = (const float*)d_in[5];
    const float* encW2  = (const float*)d_in[6];
    const float* encB2  = (const float*)d_in[7];
    const float* convW1 = (const float*)d_in[8];
    const float* convB1 = (const float*)d_in[9];
    const float* convW2 = (const float*)d_in[10];
    const float* convB2 = (const float*)d_in[11];
    const float* skipW  = (const float*)d_in[12];
    const float* skipB  = (const float*)d_in[13];
    const float* lnG    = (const float*)d_in[14];
    const float* lnB    = (const float*)d_in[15];
    const float* headW1 = (const float*)d_in[16];
    const float* headB1 = (const float*)d_in[17];
    const float* headW2 = (const float*)d_in[18];
    const float* headB2 = (const float*)d_in[19];

    const int N = in_sizes[0] / 3;      // NOTE: packing assumes N < 65536
    const int E = in_sizes[1] / 2;
    const int L = in_sizes[8] / (130 * 64);
    const int* rows = EI;
    const int* cols = EI + E;

    const int NB = (N + 63) / 64;       // buckets = 64-row agg tiles (<= 1024)

    auto align256 = [](size_t x){ return (x + 255) & ~(size_t)255; };
    char* p = (char*)d_ws;
    u16* hbf = (u16*)p;             p += align256((size_t)N * 64 * 2);
    u16* Ubf = (u16*)p;             p += align256((size_t)N * 64 * 2);
    u16* Vbf = (u16*)p;             p += align256((size_t)N * 64 * 2);
    float* agg = (float*)p;         p += align256((size_t)N * 64 * 4);
    uint2* erec = (uint2*)p;        p += align256((size_t)E * 8);
    int* countsB = (int*)p;         p += align256(1024 * 4);
    int* offsets = (int*)p;         p += align256(1032 * 4);
    int* cursorB = (int*)p;         p += align256(1024 * 4);

    // ---- build bucket-binned packed edge records (once per call) ----
    hipMemsetAsync(countsB, 0, (size_t)NB * sizeof(int), stream);
    countB_kernel<<<256, 256, 0, stream>>>(rows, countsB, E, NB);
    scanB_kernel<<<1, 1024, 0, stream>>>(countsB, offsets, cursorB, NB);
    binpack_kernel<<<(E + CHUNK - 1) / CHUNK, 1024, 0, stream>>>(rows, cols, EF, cursorB, erec, E);

    enc_kernel<<<NB, 256, 0, stream>>>(X, encW1, encB1, encW2, encB2,
                                       convW1, convB1, hbf, Ubf, Vbf, N);

    for (int li = 0; li < L; ++li){
        msg_kernel<<<NB, 256, 0, stream>>>(Ubf, Vbf, erec, offsets,
            convW1 + (size_t)li * 130 * 64,
            convW2 + (size_t)li * 64 * 64, convB2 + li * 64,
            agg, N);
        const float* w1n = (li + 1 < L) ? convW1 + (size_t)(li + 1) * 130 * 64 : nullptr;
        const float* b1n = (li + 1 < L) ? convB1 + (li + 1) * 64 : nullptr;
        update_kernel<<<NB, 256, 0, stream>>>(hbf, agg,
            skipW + (size_t)li * 64 * 64, skipB + li * 64,
            lnG + li * 64, lnB + li * 64, w1n, b1n, Ubf, Vbf, N);
    }
    head_kernel<<<NB, 256, 0, stream>>>(hbf, headW1, headB1, headW2, headB2,
                                        (float*)d_out, N);
}

// Round 6
// 392.111 us; speedup vs baseline: 4.0971x; 4.0971x over previous
//
#include <hip/hip_runtime.h>

typedef unsigned short u16;
typedef __attribute__((ext_vector_type(8))) short bf16x8;
typedef __attribute__((ext_vector_type(4))) float f32x4;

#define MFMA16(a,b,c) __builtin_amdgcn_mfma_f32_16x16x32_bf16((a),(b),(c),0,0,0)

static __device__ __forceinline__ u16 f2bf(float x){
    unsigned int u = __float_as_uint(x);
    u += 0x7FFFu + ((u >> 16) & 1u);
    return (u16)(u >> 16);
}
static __device__ __forceinline__ float bf2f(short s){
    return __uint_as_float(((unsigned int)(u16)s) << 16);
}

static __device__ __forceinline__ bf16x8 load_bfrag(const float* __restrict__ W, int ldn, int n, int k0){
    bf16x8 r;
    #pragma unroll
    for (int j = 0; j < 8; ++j) r[j] = (short)f2bf(W[(k0 + j) * ldn + n]);
    return r;
}

// ---------------- encoder: h = relu(x@W1+b1)@W2 + b2 ; emit h, U0, V0 --------
__global__ __launch_bounds__(256) void enc_kernel(
    const float* __restrict__ X, const float* __restrict__ W1, const float* __restrict__ B1,
    const float* __restrict__ W2, const float* __restrict__ B2,
    const float* __restrict__ cW1, const float* __restrict__ cB1,   // conv layer-0
    u16* __restrict__ hbf, u16* __restrict__ Ubf, u16* __restrict__ Vbf, int N)
{
    __shared__ u16 sHid[64 * 136];
    __shared__ u16 sH[64 * 72];
    const int tid = threadIdx.x;
    const int w = tid >> 6, l = tid & 63, l15 = l & 15, quad = l >> 4;

    bf16x8 bW[4][4];
    #pragma unroll
    for (int ks = 0; ks < 4; ++ks)
        #pragma unroll
        for (int f = 0; f < 4; ++f)
            bW[ks][f] = load_bfrag(W2, 64, f * 16 + l15, ks * 32 + quad * 8);
    float b2v[4];
    #pragma unroll
    for (int f = 0; f < 4; ++f) b2v[f] = B2[f * 16 + l15];

    const int nbase = blockIdx.x * 64 + w * 16;

    {
        int e = l >> 2;
        int node = nbase + e; if (node > N - 1) node = N - 1;
        float x0 = X[node * 3], x1 = X[node * 3 + 1], x2 = X[node * 3 + 2];
        int k0 = (l & 3) * 32;
        u16* dst = sHid + (w * 16 + e) * 136 + k0;
        #pragma unroll
        for (int j = 0; j < 32; ++j){
            int k = k0 + j;
            float hv = x0 * W1[k] + x1 * W1[128 + k] + x2 * W1[256 + k] + B1[k];
            dst[j] = f2bf(hv > 0.f ? hv : 0.f);
        }
    }

    f32x4 acc[4];
    #pragma unroll
    for (int f = 0; f < 4; ++f){ acc[f][0]=b2v[f]; acc[f][1]=b2v[f]; acc[f][2]=b2v[f]; acc[f][3]=b2v[f]; }
    #pragma unroll
    for (int ks = 0; ks < 4; ++ks){
        bf16x8 a = *(const bf16x8*)&sHid[(w * 16 + l15) * 136 + ks * 32 + quad * 8];
        #pragma unroll
        for (int f = 0; f < 4; ++f) acc[f] = MFMA16(a, bW[ks][f], acc[f]);
    }
    #pragma unroll
    for (int r = 0; r < 4; ++r){
        int node = nbase + quad * 4 + r;
        #pragma unroll
        for (int f = 0; f < 4; ++f){
            u16 hb = f2bf(acc[f][r]);
            sH[(w * 16 + quad * 4 + r) * 72 + f * 16 + l15] = hb;
            if (node < N) hbf[(size_t)node * 64 + f * 16 + l15] = hb;
        }
    }

    // U = h@cW1a + cB1 ; V = h@cW1b   (same-wave LDS write->read, no barrier)
    bf16x8 bA[2][4], bB[2][4];
    #pragma unroll
    for (int kk = 0; kk < 2; ++kk)
        #pragma unroll
        for (int f = 0; f < 4; ++f){
            int n = f * 16 + l15, k0 = kk * 32 + quad * 8;
            bA[kk][f] = load_bfrag(cW1,           64, n, k0);
            bB[kk][f] = load_bfrag(cW1 + 64 * 64, 64, n, k0);
        }
    float b1n[4];
    #pragma unroll
    for (int f = 0; f < 4; ++f) b1n[f] = cB1[f * 16 + l15];

    bf16x8 a0 = *(const bf16x8*)&sH[(w * 16 + l15) * 72 + quad * 8];
    bf16x8 a1 = *(const bf16x8*)&sH[(w * 16 + l15) * 72 + 32 + quad * 8];

    f32x4 ua[4], va[4];
    #pragma unroll
    for (int f = 0; f < 4; ++f){
        ua[f][0]=b1n[f]; ua[f][1]=b1n[f]; ua[f][2]=b1n[f]; ua[f][3]=b1n[f];
        va[f][0]=0.f; va[f][1]=0.f; va[f][2]=0.f; va[f][3]=0.f;
    }
    #pragma unroll
    for (int f = 0; f < 4; ++f){ ua[f] = MFMA16(a0, bA[0][f], ua[f]); va[f] = MFMA16(a0, bB[0][f], va[f]); }
    #pragma unroll
    for (int f = 0; f < 4; ++f){ ua[f] = MFMA16(a1, bA[1][f], ua[f]); va[f] = MFMA16(a1, bB[1][f], va[f]); }

    #pragma unroll
    for (int r = 0; r < 4; ++r){
        int node = nbase + quad * 4 + r;
        if (node < N){
            #pragma unroll
            for (int f = 0; f < 4; ++f){
                Ubf[(size_t)node * 64 + f * 16 + l15] = f2bf(ua[f][r]);
                Vbf[(size_t)node * 64 + f * 16 + l15] = f2bf(va[f][r]);
            }
        }
    }
}

// ---------------- bucket binning build (bucket = 64 dest rows) ---------------
// NB <= 1024 assumed (N <= 65536). int LDS atomics only (native, fast).

__global__ __launch_bounds__(256) void countB_kernel(const int* __restrict__ rows,
                                                     int* __restrict__ countsB, int E, int NB){
    __shared__ int c[1024];
    for (int i = threadIdx.x; i < NB; i += 256) c[i] = 0;
    __syncthreads();
    for (int i = blockIdx.x * 256 + threadIdx.x; i < E; i += gridDim.x * 256)
        atomicAdd(&c[rows[i] >> 6], 1);
    __syncthreads();
    for (int i = threadIdx.x; i < NB; i += 256){
        int v = c[i];
        if (v) atomicAdd(&countsB[i], v);
    }
}

__global__ __launch_bounds__(1024) void scanB_kernel(const int* __restrict__ countsB,
                                                     int* __restrict__ offsets,
                                                     int* __restrict__ cursorB, int NB){
    __shared__ int sc[1024];
    const int tid = threadIdx.x;
    int x = (tid < NB) ? countsB[tid] : 0;
    sc[tid] = x;
    __syncthreads();
    for (int d = 1; d < 1024; d <<= 1){
        int v = (tid >= d) ? sc[tid - d] : 0;
        __syncthreads();
        sc[tid] += v;
        __syncthreads();
    }
    int excl = sc[tid] - x;
    if (tid < NB){ offsets[tid] = excl; cursorB[tid] = excl; }
    if (tid == NB - 1) offsets[NB] = sc[tid];
}

#define CHUNK 8192

// chunk-local counting sort by bucket, then contiguous run writes per bucket
__global__ __launch_bounds__(1024) void binpack_kernel(
    const int* __restrict__ rows, const int* __restrict__ cols,
    const float* __restrict__ EF, int* __restrict__ cursorB,
    uint2* __restrict__ erec, int E)
{
    __shared__ u16 sRow[CHUNK];
    __shared__ u16 sPerm[CHUNK];
    __shared__ int cntA[1024], cntE[1024], cntC[1024], baseB[1024], sc[1024];
    const int tid = threadIdx.x;
    const int cbase = blockIdx.x * CHUNK;
    int C = E - cbase; if (C > CHUNK) C = CHUNK;
    if (C <= 0) return;

    cntA[tid] = 0;
    __syncthreads();
    for (int k = tid; k < C; k += 1024){
        int r = rows[cbase + k];
        sRow[k] = (u16)r;
        atomicAdd(&cntA[r >> 6], 1);
    }
    __syncthreads();
    sc[tid] = cntA[tid];
    __syncthreads();
    for (int d = 1; d < 1024; d <<= 1){
        int v = (tid >= d) ? sc[tid - d] : 0;
        __syncthreads();
        sc[tid] += v;
        __syncthreads();
    }
    int excl = sc[tid] - cntA[tid];
    cntE[tid] = excl;
    cntC[tid] = excl;
    if (cntA[tid] > 0) baseB[tid] = atomicAdd(&cursorB[tid], cntA[tid]);
    __syncthreads();
    for (int k = tid; k < C; k += 1024){
        int b = sRow[k] >> 6;
        int p = atomicAdd(&cntC[b], 1);
        sPerm[p] = (u16)k;
    }
    __syncthreads();
    for (int p = tid; p < C; p += 1024){
        int k = sPerm[p];
        int i = cbase + k;
        int r = sRow[k];
        int b = r >> 6;
        float2 ef = *(const float2*)&EF[2 * i];
        uint2 v;
        v.x = (unsigned)r | ((unsigned)cols[i] << 16);
        v.y = (unsigned)f2bf(ef.x) | ((unsigned)f2bf(ef.y) << 16);
        erec[baseB[b] + (p - cntE[b])] = v;
    }
}

// ----- rowsort: one block per bucket; counting sort records by row (&63) -----
#define SCH 2048
__global__ __launch_bounds__(256) void rowsort_kernel(uint2* __restrict__ erec,
                                                      const int* __restrict__ offsets){
    __shared__ int cnt[64];
    __shared__ int base[64];
    const int tid = threadIdx.x;
    const int b = blockIdx.x;
    const int start = offsets[b], end = offsets[b + 1];
    for (int done = start; done < end; done += SCH){
        int C = end - done; if (C > SCH) C = SCH;
        if (tid < 64) cnt[tid] = 0;
        __syncthreads();
        uint2 rec[8]; int key[8], pos[8];
        #pragma unroll
        for (int i = 0; i < 8; ++i){
            int k = tid + i * 256;
            if (k < C){
                uint2 r = erec[done + k];
                rec[i] = r;
                key[i] = (int)(r.x & 63u);
                pos[i] = atomicAdd(&cnt[key[i]], 1);
            } else key[i] = -1;
        }
        __syncthreads();
        if (tid < 64){
            int x = cnt[tid];
            int inc = x;
            #pragma unroll
            for (int d = 1; d < 64; d <<= 1){
                int t = __shfl_up(inc, d);
                if (tid >= d) inc += t;
            }
            base[tid] = inc - x;
        }
        __syncthreads();
        #pragma unroll
        for (int i = 0; i < 8; ++i)
            if (key[i] >= 0) erec[done + base[key[i]] + pos[i]] = rec[i];
        __syncthreads();
    }
}

// issue U/V gathers for a record (loads start here; waited at first use)
#define ISSUE_UV(recv, U0, U1, V0, V1) do {                                  \
    int rr_ = (int)((recv).x & 0xFFFFu); if (rr_ == 0xFFFF) rr_ = 0;         \
    int cc_ = (int)((recv).x >> 16);                                         \
    const u16* pu_ = Ubf + (size_t)rr_ * 64 + quad * 8;                      \
    const u16* pv_ = Vbf + (size_t)cc_ * 64 + quad * 8;                      \
    U0 = *(const bf16x8*)(pu_);                                              \
    U1 = *(const bf16x8*)(pu_ + 32);                                         \
    V0 = *(const bf16x8*)(pv_);                                              \
    V1 = *(const bf16x8*)(pv_ + 32);                                         \
} while (0)

// ------ message: bucket per block; segmented reduce + sparse global atomics --
__global__ __launch_bounds__(256, 3) void msg_kernel(
    const u16* __restrict__ Ubf, const u16* __restrict__ Vbf,
    const uint2* __restrict__ erec, const int* __restrict__ offsets,
    const float* __restrict__ W1,   // [130][64] of this layer (ef rows 128,129)
    const float* __restrict__ W2, const float* __restrict__ B2,
    float* __restrict__ agg, int N)
{
    __shared__ float sMsg[4][16 * 68];
    const int tid = threadIdx.x;
    const int w = tid >> 6, l = tid & 63, l15 = l & 15, quad = l >> 4;
    const int w16 = w * 16;

    bf16x8 bW2[2][4];
    #pragma unroll
    for (int kk = 0; kk < 2; ++kk)
        #pragma unroll
        for (int f = 0; f < 4; ++f)
            bW2[kk][f] = load_bfrag(W2, 64, f * 16 + l15, kk * 32 + quad * 8);
    float bias2[4];
    #pragma unroll
    for (int f = 0; f < 4; ++f) bias2[f] = B2[f * 16 + l15];

    const float* Wc0 = W1 + 128 * 64;
    const float* Wc1 = W1 + 129 * 64;
    float e0l[8], e0h[8], e1l[8], e1h[8];
    #pragma unroll
    for (int j = 0; j < 8; ++j){
        int kl = quad * 8 + j;
        e0l[j] = Wc0[kl];       e0h[j] = Wc0[32 + kl];
        e1l[j] = Wc1[kl];       e1h[j] = Wc1[32 + kl];
    }

    const int b = blockIdx.x;
    const int start = offsets[b], end = offsets[b + 1];
    const int nt = (end - start + 63) >> 6;
    if (nt <= 0) return;
    float* myMsg = sMsg[w];

    auto LOADREC = [&](int t) -> uint2 {
        int e = start + t * 64 + w16 + l15;
        if (e < end) return erec[e];
        uint2 s; s.x = 0x0000FFFFu; s.y = 0u; return s;
    };

    // 2-deep pipeline: rec two ahead, U/V gathers one ahead
    uint2 recA = LOADREC(0);
    uint2 recB = (nt > 1) ? LOADREC(1) : recA;
    bf16x8 u0, u1, v0, v1;
    ISSUE_UV(recA, u0, u1, v0, v1);

    for (int t = 0; t < nt; ++t){
        uint2 recC = LOADREC(t + 2 < nt ? t + 2 : nt - 1);
        bf16x8 nu0, nu1, nv0, nv1;
        ISSUE_UV(recB, nu0, nu1, nv0, nv1);     // next tile's gathers in flight

        int rn_raw = (int)(recA.x & 0xFFFFu);
        int rn = (rn_raw == 0xFFFF) ? -1 : rn_raw;
        float ef0 = bf2f((short)(recA.y & 0xFFFFu));
        float ef1 = bf2f((short)(recA.y >> 16));

        float hA[8], hB[8];
        #pragma unroll
        for (int j = 0; j < 8; ++j){
            hA[j] = fmaf(ef1, e1l[j], ef0 * e0l[j]);
            hB[j] = fmaf(ef1, e1h[j], ef0 * e0h[j]);
        }

        bf16x8 a0, a1;
        #pragma unroll
        for (int j = 0; j < 8; ++j){
            float xl = hA[j] + bf2f(u0[j]) + bf2f(v0[j]);
            float xh = hB[j] + bf2f(u1[j]) + bf2f(v1[j]);
            a0[j] = (short)f2bf(xl > 0.f ? xl : 0.f);
            a1[j] = (short)f2bf(xh > 0.f ? xh : 0.f);
        }

        f32x4 m[4];
        #pragma unroll
        for (int f = 0; f < 4; ++f){ m[f][0]=bias2[f]; m[f][1]=bias2[f]; m[f][2]=bias2[f]; m[f][3]=bias2[f]; }
        #pragma unroll
        for (int f = 0; f < 4; ++f) m[f] = MFMA16(a0, bW2[0][f], m[f]);
        #pragma unroll
        for (int f = 0; f < 4; ++f) m[f] = MFMA16(a1, bW2[1][f], m[f]);

        // C-layout messages -> LDS so lane = feature
        #pragma unroll
        for (int f = 0; f < 4; ++f)
            #pragma unroll
            for (int r = 0; r < 4; ++r)
                myMsg[(quad * 4 + r) * 68 + f * 16 + l15] = m[f][r];

        // segmented reduction over 16 ROW-SORTED edges -> sparse global atomics
        float accv = 0.f;
        int cur = __shfl(rn, 0);
        #pragma unroll
        for (int j = 0; j < 16; ++j){
            int rj = __shfl(rn, j);
            if (rj != cur){
                if (cur >= 0) atomicAdd(agg + (size_t)cur * 64 + l, accv);
                accv = 0.f; cur = rj;
            }
            accv += myMsg[j * 68 + l];
        }
        if (cur >= 0) atomicAdd(agg + (size_t)cur * 64 + l, accv);

        recA = recB; recB = recC;
        u0 = nu0; u1 = nu1; v0 = nv0; v1 = nv1;
    }
}

// -- update: h = relu(LN(agg + h@SW + SB)); zero agg; emit U,V for next layer -
__global__ __launch_bounds__(256) void update_kernel(
    u16* __restrict__ hbf, float* __restrict__ agg,
    const float* __restrict__ SW, const float* __restrict__ SB,
    const float* __restrict__ LG, const float* __restrict__ LB,
    const float* __restrict__ cW1, const float* __restrict__ cB1,  // next layer (may be null)
    u16* __restrict__ Ubf, u16* __restrict__ Vbf, int N)
{
    __shared__ u16 sH[64 * 72];
    const int tid = threadIdx.x;
    const int w = tid >> 6, l = tid & 63, l15 = l & 15, quad = l >> 4;

    bf16x8 bW[2][4];
    #pragma unroll
    for (int kk = 0; kk < 2; ++kk)
        #pragma unroll
        for (int f = 0; f < 4; ++f)
            bW[kk][f] = load_bfrag(SW, 64, f * 16 + l15, kk * 32 + quad * 8);
    float sb[4], lg[4], lb[4];
    #pragma unroll
    for (int f = 0; f < 4; ++f){
        int n = f * 16 + l15;
        sb[f] = SB[n]; lg[f] = LG[n]; lb[f] = LB[n];
    }

    const int nbase = blockIdx.x * 64 + w * 16;
    int na = nbase + l15; if (na > N - 1) na = N - 1;
    const u16* pa = hbf + (size_t)na * 64 + quad * 8;
    bf16x8 h0 = *(const bf16x8*)pa;
    bf16x8 h1 = *(const bf16x8*)(pa + 32);

    f32x4 acc[4] = {};
    #pragma unroll
    for (int f = 0; f < 4; ++f) acc[f] = MFMA16(h0, bW[0][f], acc[f]);
    #pragma unroll
    for (int f = 0; f < 4; ++f) acc[f] = MFMA16(h1, bW[1][f], acc[f]);

    float vals[4][4];
    #pragma unroll
    for (int r = 0; r < 4; ++r){
        int node = nbase + quad * 4 + r; if (node > N - 1) node = N - 1;
        #pragma unroll
        for (int f = 0; f < 4; ++f)
            vals[f][r] = acc[f][r] + sb[f] + agg[(size_t)node * 64 + f * 16 + l15];
    }

    #pragma unroll
    for (int r = 0; r < 4; ++r){
        float s  = vals[0][r] + vals[1][r] + vals[2][r] + vals[3][r];
        float sq = vals[0][r]*vals[0][r] + vals[1][r]*vals[1][r]
                 + vals[2][r]*vals[2][r] + vals[3][r]*vals[3][r];
        #pragma unroll
        for (int msk = 1; msk < 16; msk <<= 1){
            s  += __shfl_xor(s,  msk);
            sq += __shfl_xor(sq, msk);
        }
        float mean = s * (1.f / 64.f);
        float var  = sq * (1.f / 64.f) - mean * mean;
        float rstd = rsqrtf(var + 1e-5f);
        int node = nbase + quad * 4 + r;
        #pragma unroll
        for (int f = 0; f < 4; ++f){
            float hv = (vals[f][r] - mean) * rstd * lg[f] + lb[f];
            hv = hv > 0.f ? hv : 0.f;
            u16 hb = f2bf(hv);
            sH[(w * 16 + quad * 4 + r) * 72 + f * 16 + l15] = hb;
            if (node < N){
                hbf[(size_t)node * 64 + f * 16 + l15] = hb;
                agg[(size_t)node * 64 + f * 16 + l15] = 0.f;   // ready for next layer
            }
        }
    }

    if (cW1){
        bf16x8 bA[2][4], bB[2][4];
        #pragma unroll
        for (int kk = 0; kk < 2; ++kk)
            #pragma unroll
            for (int f = 0; f < 4; ++f){
                int n = f * 16 + l15, k0 = kk * 32 + quad * 8;
                bA[kk][f] = load_bfrag(cW1,           64, n, k0);
                bB[kk][f] = load_bfrag(cW1 + 64 * 64, 64, n, k0);
            }
        float b1n[4];
        #pragma unroll
        for (int f = 0; f < 4; ++f) b1n[f] = cB1[f * 16 + l15];

        bf16x8 a0 = *(const bf16x8*)&sH[(w * 16 + l15) * 72 + quad * 8];
        bf16x8 a1 = *(const bf16x8*)&sH[(w * 16 + l15) * 72 + 32 + quad * 8];

        f32x4 ua[4], va[4];
        #pragma unroll
        for (int f = 0; f < 4; ++f){
            ua[f][0]=b1n[f]; ua[f][1]=b1n[f]; ua[f][2]=b1n[f]; ua[f][3]=b1n[f];
            va[f][0]=0.f; va[f][1]=0.f; va[f][2]=0.f; va[f][3]=0.f;
        }
        #pragma unroll
        for (int f = 0; f < 4; ++f){ ua[f] = MFMA16(a0, bA[0][f], ua[f]); va[f] = MFMA16(a0, bB[0][f], va[f]); }
        #pragma unroll
        for (int f = 0; f < 4; ++f){ ua[f] = MFMA16(a1, bA[1][f], ua[f]); va[f] = MFMA16(a1, bB[1][f], va[f]); }

        #pragma unroll
        for (int r = 0; r < 4; ++r){
            int node = nbase + quad * 4 + r;
            if (node < N){
                #pragma unroll
                for (int f = 0; f < 4; ++f){
                    Ubf[(size_t)node * 64 + f * 16 + l15] = f2bf(ua[f][r]);
                    Vbf[(size_t)node * 64 + f * 16 + l15] = f2bf(va[f][r]);
                }
            }
        }
    }
}

// ---------------- head: out = relu(h@W1+b1)@W2 + b2  [N][8] f32 --------------
__global__ __launch_bounds__(256) void head_kernel(
    const u16* __restrict__ hbf,
    const float* __restrict__ W1, const float* __restrict__ B1,
    const float* __restrict__ W2, const float* __restrict__ B2,
    float* __restrict__ out, int N)
{
    __shared__ u16 sT[64 * 72];
    const int tid = threadIdx.x;
    const int w = tid >> 6, l = tid & 63, l15 = l & 15, quad = l >> 4;

    bf16x8 bW1[2][4];
    #pragma unroll
    for (int kk = 0; kk < 2; ++kk)
        #pragma unroll
        for (int f = 0; f < 4; ++f)
            bW1[kk][f] = load_bfrag(W1, 64, f * 16 + l15, kk * 32 + quad * 8);
    float b1v[4];
    #pragma unroll
    for (int f = 0; f < 4; ++f) b1v[f] = B1[f * 16 + l15];

    bf16x8 bW2[2];
    #pragma unroll
    for (int kk = 0; kk < 2; ++kk)
        #pragma unroll
        for (int j = 0; j < 8; ++j){
            int k = kk * 32 + quad * 8 + j;
            bW2[kk][j] = (l15 < 8) ? (short)f2bf(W2[k * 8 + l15]) : (short)0;
        }
    float b2v = (l15 < 8) ? B2[l15] : 0.f;

    const int nbase = blockIdx.x * 64 + w * 16;
    int na = nbase + l15; if (na > N - 1) na = N - 1;
    const u16* pa = hbf + (size_t)na * 64 + quad * 8;
    bf16x8 a0 = *(const bf16x8*)pa;
    bf16x8 a1 = *(const bf16x8*)(pa + 32);

    f32x4 acc[4];
    #pragma unroll
    for (int f = 0; f < 4; ++f){ acc[f][0]=b1v[f]; acc[f][1]=b1v[f]; acc[f][2]=b1v[f]; acc[f][3]=b1v[f]; }
    #pragma unroll
    for (int f = 0; f < 4; ++f) acc[f] = MFMA16(a0, bW1[0][f], acc[f]);
    #pragma unroll
    for (int f = 0; f < 4; ++f) acc[f] = MFMA16(a1, bW1[1][f], acc[f]);

    u16* myT = sT + (w * 16) * 72;
    #pragma unroll
    for (int f = 0; f < 4; ++f)
        #pragma unroll
        for (int r = 0; r < 4; ++r){
            float v = acc[f][r] > 0.f ? acc[f][r] : 0.f;
            myT[(quad * 4 + r) * 72 + f * 16 + l15] = f2bf(v);
        }

    f32x4 o = { b2v, b2v, b2v, b2v };
    #pragma unroll
    for (int kk = 0; kk < 2; ++kk){
        bf16x8 a = *(const bf16x8*)&myT[l15 * 72 + kk * 32 + quad * 8];
        o = MFMA16(a, bW2[kk], o);
    }
    #pragma unroll
    for (int r = 0; r < 4; ++r){
        int node = nbase + quad * 4 + r;
        if (node < N && l15 < 8)
            out[(size_t)node * 8 + l15] = o[r];
    }
}

extern "C" void kernel_launch(void* const* d_in, const int* in_sizes, int n_in,
                              void* d_out, int out_size, void* d_ws, size_t ws_size,
                              hipStream_t stream)
{
    const float* X      = (const float*)d_in[0];
    const int*   EI     = (const int*)d_in[1];
    const float* EF     = (const float*)d_in[2];
    const float* encW1  = (const float*)d_in[4];
    const float* encB1  = (const float*)d_in[5];
    const float* encW2  = (const float*)d_in[6];
    const float* encB2  = (const float*)d_in[7];
    const float* convW1 = (const float*)d_in[8];
    const float* convB1 = (const float*)d_in[9];
    const float* convW2 = (const float*)d_in[10];
    const float* convB2 = (const float*)d_in[11];
    const float* skipW  = (const float*)d_in[12];
    const float* skipB  = (const float*)d_in[13];
    const float* lnG    = (const float*)d_in[14];
    const float* lnB    = (const float*)d_in[15];
    const float* headW1 = (const float*)d_in[16];
    const float* headB1 = (const float*)d_in[17];
    const float* headW2 = (const float*)d_in[18];
    const float* headB2 = (const float*)d_in[19];

    const int N = in_sizes[0] / 3;      // NOTE: packing assumes N < 65535
    const int E = in_sizes[1] / 2;
    const int L = in_sizes[8] / (130 * 64);
    const int* rows = EI;
    const int* cols = EI + E;

    const int NB = (N + 63) / 64;       // buckets = 64-row tiles (<= 1024)

    auto align256 = [](size_t x){ return (x + 255) & ~(size_t)255; };
    char* p = (char*)d_ws;
    u16* hbf = (u16*)p;             p += align256((size_t)N * 64 * 2);
    u16* Ubf = (u16*)p;             p += align256((size_t)N * 64 * 2);
    u16* Vbf = (u16*)p;             p += align256((size_t)N * 64 * 2);
    float* agg = (float*)p;         p += align256((size_t)N * 64 * 4);
    uint2* erec = (uint2*)p;        p += align256((size_t)E * 8);
    int* countsB = (int*)p;         p += align256(1024 * 4);
    int* offsets = (int*)p;         p += align256(1032 * 4);
    int* cursorB = (int*)p;         p += align256(1024 * 4);

    // ---- build bucket-binned, row-sorted packed edge records ----
    hipMemsetAsync(countsB, 0, (size_t)NB * sizeof(int), stream);
    countB_kernel<<<256, 256, 0, stream>>>(rows, countsB, E, NB);
    scanB_kernel<<<1, 1024, 0, stream>>>(countsB, offsets, cursorB, NB);
    binpack_kernel<<<(E + CHUNK - 1) / CHUNK, 1024, 0, stream>>>(rows, cols, EF, cursorB, erec, E);
    rowsort_kernel<<<NB, 256, 0, stream>>>(erec, offsets);

    hipMemsetAsync(agg, 0, (size_t)N * 64 * sizeof(float), stream);
    enc_kernel<<<NB, 256, 0, stream>>>(X, encW1, encB1, encW2, encB2,
                                       convW1, convB1, hbf, Ubf, Vbf, N);

    for (int li = 0; li < L; ++li){
        msg_kernel<<<NB, 256, 0, stream>>>(Ubf, Vbf, erec, offsets,
            convW1 + (size_t)li * 130 * 64,
            convW2 + (size_t)li * 64 * 64, convB2 + li * 64,
            agg, N);
        const float* w1n = (li + 1 < L) ? convW1 + (size_t)(li + 1) * 130 * 64 : nullptr;
        const float* b1n = (li + 1 < L) ? convB1 + (li + 1) * 64 : nullptr;
        update_kernel<<<NB, 256, 0, stream>>>(hbf, agg,
            skipW + (size_t)li * 64 * 64, skipB + li * 64,
            lnG + li * 64, lnB + li * 64, w1n, b1n, Ubf, Vbf, N);
    }
    head_kernel<<<NB, 256, 0, stream>>>(hbf, headW1, headB1, headW2, headB2,
                                        (float*)d_out, N);
}

// Round 7
// 359.068 us; speedup vs baseline: 4.4741x; 1.0920x over previous
//
#include <hip/hip_runtime.h>

typedef unsigned short u16;
typedef __attribute__((ext_vector_type(8))) short bf16x8;
typedef __attribute__((ext_vector_type(4))) float f32x4;

#define MFMA16(a,b,c) __builtin_amdgcn_mfma_f32_16x16x32_bf16((a),(b),(c),0,0,0)

static __device__ __forceinline__ u16 f2bf(float x){
    unsigned int u = __float_as_uint(x);
    u += 0x7FFFu + ((u >> 16) & 1u);
    return (u16)(u >> 16);
}
static __device__ __forceinline__ float bf2f(short s){
    return __uint_as_float(((unsigned int)(u16)s) << 16);
}

static __device__ __forceinline__ bf16x8 load_bfrag(const float* __restrict__ W, int ldn, int n, int k0){
    bf16x8 r;
    #pragma unroll
    for (int j = 0; j < 8; ++j) r[j] = (short)f2bf(W[(k0 + j) * ldn + n]);
    return r;
}

// ---------------- encoder: h = relu(x@W1+b1)@W2 + b2 ; emit h, U0, V0 --------
__global__ __launch_bounds__(256) void enc_kernel(
    const float* __restrict__ X, const float* __restrict__ W1, const float* __restrict__ B1,
    const float* __restrict__ W2, const float* __restrict__ B2,
    const float* __restrict__ cW1, const float* __restrict__ cB1,   // conv layer-0
    u16* __restrict__ hbf, u16* __restrict__ Ubf, u16* __restrict__ Vbf, int N)
{
    __shared__ u16 sHid[64 * 136];
    __shared__ u16 sH[64 * 72];
    const int tid = threadIdx.x;
    const int w = tid >> 6, l = tid & 63, l15 = l & 15, quad = l >> 4;

    bf16x8 bW[4][4];
    #pragma unroll
    for (int ks = 0; ks < 4; ++ks)
        #pragma unroll
        for (int f = 0; f < 4; ++f)
            bW[ks][f] = load_bfrag(W2, 64, f * 16 + l15, ks * 32 + quad * 8);
    float b2v[4];
    #pragma unroll
    for (int f = 0; f < 4; ++f) b2v[f] = B2[f * 16 + l15];

    const int nbase = blockIdx.x * 64 + w * 16;

    {
        int e = l >> 2;
        int node = nbase + e; if (node > N - 1) node = N - 1;
        float x0 = X[node * 3], x1 = X[node * 3 + 1], x2 = X[node * 3 + 2];
        int k0 = (l & 3) * 32;
        u16* dst = sHid + (w * 16 + e) * 136 + k0;
        #pragma unroll
        for (int j = 0; j < 32; ++j){
            int k = k0 + j;
            float hv = x0 * W1[k] + x1 * W1[128 + k] + x2 * W1[256 + k] + B1[k];
            dst[j] = f2bf(hv > 0.f ? hv : 0.f);
        }
    }

    f32x4 acc[4];
    #pragma unroll
    for (int f = 0; f < 4; ++f){ acc[f][0]=b2v[f]; acc[f][1]=b2v[f]; acc[f][2]=b2v[f]; acc[f][3]=b2v[f]; }
    #pragma unroll
    for (int ks = 0; ks < 4; ++ks){
        bf16x8 a = *(const bf16x8*)&sHid[(w * 16 + l15) * 136 + ks * 32 + quad * 8];
        #pragma unroll
        for (int f = 0; f < 4; ++f) acc[f] = MFMA16(a, bW[ks][f], acc[f]);
    }
    #pragma unroll
    for (int r = 0; r < 4; ++r){
        int node = nbase + quad * 4 + r;
        #pragma unroll
        for (int f = 0; f < 4; ++f){
            u16 hb = f2bf(acc[f][r]);
            sH[(w * 16 + quad * 4 + r) * 72 + f * 16 + l15] = hb;
            if (node < N) hbf[(size_t)node * 64 + f * 16 + l15] = hb;
        }
    }

    // U = h@cW1a + cB1 ; V = h@cW1b   (same-wave LDS write->read, no barrier)
    bf16x8 bA[2][4], bB[2][4];
    #pragma unroll
    for (int kk = 0; kk < 2; ++kk)
        #pragma unroll
        for (int f = 0; f < 4; ++f){
            int n = f * 16 + l15, k0 = kk * 32 + quad * 8;
            bA[kk][f] = load_bfrag(cW1,           64, n, k0);
            bB[kk][f] = load_bfrag(cW1 + 64 * 64, 64, n, k0);
        }
    float b1n[4];
    #pragma unroll
    for (int f = 0; f < 4; ++f) b1n[f] = cB1[f * 16 + l15];

    bf16x8 a0 = *(const bf16x8*)&sH[(w * 16 + l15) * 72 + quad * 8];
    bf16x8 a1 = *(const bf16x8*)&sH[(w * 16 + l15) * 72 + 32 + quad * 8];

    f32x4 ua[4], va[4];
    #pragma unroll
    for (int f = 0; f < 4; ++f){
        ua[f][0]=b1n[f]; ua[f][1]=b1n[f]; ua[f][2]=b1n[f]; ua[f][3]=b1n[f];
        va[f][0]=0.f; va[f][1]=0.f; va[f][2]=0.f; va[f][3]=0.f;
    }
    #pragma unroll
    for (int f = 0; f < 4; ++f){ ua[f] = MFMA16(a0, bA[0][f], ua[f]); va[f] = MFMA16(a0, bB[0][f], va[f]); }
    #pragma unroll
    for (int f = 0; f < 4; ++f){ ua[f] = MFMA16(a1, bA[1][f], ua[f]); va[f] = MFMA16(a1, bB[1][f], va[f]); }

    #pragma unroll
    for (int r = 0; r < 4; ++r){
        int node = nbase + quad * 4 + r;
        if (node < N){
            #pragma unroll
            for (int f = 0; f < 4; ++f){
                Ubf[(size_t)node * 64 + f * 16 + l15] = f2bf(ua[f][r]);
                Vbf[(size_t)node * 64 + f * 16 + l15] = f2bf(va[f][r]);
            }
        }
    }
}

// ---------------- bucket binning build (bucket = 64 dest rows) ---------------
// NB <= 1024 assumed (N <= 65536). int LDS atomics only (native, fast).

__global__ __launch_bounds__(256) void countB_kernel(const int* __restrict__ rows,
                                                     int* __restrict__ countsB, int E, int NB){
    __shared__ int c[1024];
    for (int i = threadIdx.x; i < NB; i += 256) c[i] = 0;
    __syncthreads();
    for (int i = blockIdx.x * 256 + threadIdx.x; i < E; i += gridDim.x * 256)
        atomicAdd(&c[rows[i] >> 6], 1);
    __syncthreads();
    for (int i = threadIdx.x; i < NB; i += 256){
        int v = c[i];
        if (v) atomicAdd(&countsB[i], v);
    }
}

__global__ __launch_bounds__(1024) void scanB_kernel(const int* __restrict__ countsB,
                                                     int* __restrict__ offsets,
                                                     int* __restrict__ cursorB, int NB){
    __shared__ int sc[1024];
    const int tid = threadIdx.x;
    int x = (tid < NB) ? countsB[tid] : 0;
    sc[tid] = x;
    __syncthreads();
    for (int d = 1; d < 1024; d <<= 1){
        int v = (tid >= d) ? sc[tid - d] : 0;
        __syncthreads();
        sc[tid] += v;
        __syncthreads();
    }
    int excl = sc[tid] - x;
    if (tid < NB){ offsets[tid] = excl; cursorB[tid] = excl; }
    if (tid == NB - 1) offsets[NB] = sc[tid];
}

#define CHUNK 8192

// chunk-local counting sort by bucket, then contiguous run writes per bucket
__global__ __launch_bounds__(1024) void binpack_kernel(
    const int* __restrict__ rows, const int* __restrict__ cols,
    const float* __restrict__ EF, int* __restrict__ cursorB,
    uint2* __restrict__ erec, int E)
{
    __shared__ u16 sRow[CHUNK];
    __shared__ u16 sPerm[CHUNK];
    __shared__ int cntA[1024], cntE[1024], cntC[1024], baseB[1024], sc[1024];
    const int tid = threadIdx.x;
    const int cbase = blockIdx.x * CHUNK;
    int C = E - cbase; if (C > CHUNK) C = CHUNK;
    if (C <= 0) return;

    cntA[tid] = 0;
    __syncthreads();
    for (int k = tid; k < C; k += 1024){
        int r = rows[cbase + k];
        sRow[k] = (u16)r;
        atomicAdd(&cntA[r >> 6], 1);
    }
    __syncthreads();
    sc[tid] = cntA[tid];
    __syncthreads();
    for (int d = 1; d < 1024; d <<= 1){
        int v = (tid >= d) ? sc[tid - d] : 0;
        __syncthreads();
        sc[tid] += v;
        __syncthreads();
    }
    int excl = sc[tid] - cntA[tid];
    cntE[tid] = excl;
    cntC[tid] = excl;
    if (cntA[tid] > 0) baseB[tid] = atomicAdd(&cursorB[tid], cntA[tid]);
    __syncthreads();
    for (int k = tid; k < C; k += 1024){
        int b = sRow[k] >> 6;
        int p = atomicAdd(&cntC[b], 1);
        sPerm[p] = (u16)k;
    }
    __syncthreads();
    for (int p = tid; p < C; p += 1024){
        int k = sPerm[p];
        int i = cbase + k;
        int r = sRow[k];
        int b = r >> 6;
        float2 ef = *(const float2*)&EF[2 * i];
        uint2 v;
        v.x = (unsigned)r | ((unsigned)cols[i] << 16);
        v.y = (unsigned)f2bf(ef.x) | ((unsigned)f2bf(ef.y) << 16);
        erec[baseB[b] + (p - cntE[b])] = v;
    }
}

// ----- rowsort: one block per bucket; counting sort records by row (&63) -----
#define SCH 2048
__global__ __launch_bounds__(256) void rowsort_kernel(uint2* __restrict__ erec,
                                                      const int* __restrict__ offsets){
    __shared__ int cnt[64];
    __shared__ int base[64];
    const int tid = threadIdx.x;
    const int b = blockIdx.x;
    const int start = offsets[b], end = offsets[b + 1];
    for (int done = start; done < end; done += SCH){
        int C = end - done; if (C > SCH) C = SCH;
        if (tid < 64) cnt[tid] = 0;
        __syncthreads();
        uint2 rec[8]; int key[8], pos[8];
        #pragma unroll
        for (int i = 0; i < 8; ++i){
            int k = tid + i * 256;
            if (k < C){
                uint2 r = erec[done + k];
                rec[i] = r;
                key[i] = (int)(r.x & 63u);
                pos[i] = atomicAdd(&cnt[key[i]], 1);
            } else key[i] = -1;
        }
        __syncthreads();
        if (tid < 64){
            int x = cnt[tid];
            int inc = x;
            #pragma unroll
            for (int d = 1; d < 64; d <<= 1){
                int t = __shfl_up(inc, d);
                if (tid >= d) inc += t;
            }
            base[tid] = inc - x;
        }
        __syncthreads();
        #pragma unroll
        for (int i = 0; i < 8; ++i)
            if (key[i] >= 0) erec[done + base[key[i]] + pos[i]] = rec[i];
        __syncthreads();
    }
}

// issue U/V gathers for a record (loads start here; waited at first use)
#define ISSUE_UV(recv, U0, U1, V0, V1) do {                                  \
    int rr_ = (int)((recv).x & 0xFFFFu); if (rr_ == 0xFFFF) rr_ = 0;         \
    int cc_ = (int)((recv).x >> 16);                                         \
    const u16* pu_ = Ubf + (size_t)rr_ * 64 + quad * 8;                      \
    const u16* pv_ = Vbf + (size_t)cc_ * 64 + quad * 8;                      \
    U0 = *(const bf16x8*)(pu_);                                              \
    U1 = *(const bf16x8*)(pu_ + 32);                                         \
    V0 = *(const bf16x8*)(pv_);                                              \
    V1 = *(const bf16x8*)(pv_ + 32);                                         \
} while (0)

// pack 8 floats -> bf16x8 via v_cvt_pk_bf16_f32 (RTNE, 4 instrs)
#define PACK8(dst, x) do {                                                   \
    union { bf16x8 v; unsigned int d[4]; } _u;                               \
    asm("v_cvt_pk_bf16_f32 %0, %1, %2" : "=v"(_u.d[0]) : "v"(x[0]), "v"(x[1])); \
    asm("v_cvt_pk_bf16_f32 %0, %1, %2" : "=v"(_u.d[1]) : "v"(x[2]), "v"(x[3])); \
    asm("v_cvt_pk_bf16_f32 %0, %1, %2" : "=v"(_u.d[2]) : "v"(x[4]), "v"(x[5])); \
    asm("v_cvt_pk_bf16_f32 %0, %1, %2" : "=v"(_u.d[3]) : "v"(x[6]), "v"(x[7])); \
    dst = _u.v;                                                              \
} while (0)

// ------ message: 2 blocks per bucket; segmented reduce + sparse gl atomics ---
__global__ __launch_bounds__(256, 3) void msg_kernel(
    const u16* __restrict__ Ubf, const u16* __restrict__ Vbf,
    const uint2* __restrict__ erec, const int* __restrict__ offsets,
    const float* __restrict__ W1,   // [130][64] of this layer (ef rows 128,129)
    const float* __restrict__ W2, const float* __restrict__ B2,
    float* __restrict__ agg, int N)
{
    __shared__ float sMsg[4][16 * 68];
    const int tid = threadIdx.x;
    const int w = tid >> 6, l = tid & 63, l15 = l & 15, quad = l >> 4;
    const int w16 = w * 16;

    bf16x8 bW2[2][4];
    #pragma unroll
    for (int kk = 0; kk < 2; ++kk)
        #pragma unroll
        for (int f = 0; f < 4; ++f)
            bW2[kk][f] = load_bfrag(W2, 64, f * 16 + l15, kk * 32 + quad * 8);
    float bias2[4];
    #pragma unroll
    for (int f = 0; f < 4; ++f) bias2[f] = B2[f * 16 + l15];

    const float* Wc0 = W1 + 128 * 64;
    const float* Wc1 = W1 + 129 * 64;
    float e0l[8], e0h[8], e1l[8], e1h[8];
    #pragma unroll
    for (int j = 0; j < 8; ++j){
        int kl = quad * 8 + j;
        e0l[j] = Wc0[kl];       e0h[j] = Wc0[32 + kl];
        e1l[j] = Wc1[kl];       e1h[j] = Wc1[32 + kl];
    }

    const int b   = blockIdx.x >> 1;
    const int seg = blockIdx.x & 1;
    const int start = offsets[b], end = offsets[b + 1];
    const int nt = (end - start + 63) >> 6;
    const int ntA = (nt + 1) >> 1;
    const int t0 = seg ? ntA : 0;
    const int t1 = seg ? nt : ntA;
    if (t0 >= t1) return;
    float* myMsg = sMsg[w];

    auto LOADREC = [&](int t) -> uint2 {
        int e = start + t * 64 + w16 + l15;
        if (e < end) return erec[e];
        uint2 s; s.x = 0x0000FFFFu; s.y = 0u; return s;
    };

    // 2-deep pipeline: rec two ahead, U/V gathers one ahead
    uint2 recA = LOADREC(t0);
    uint2 recB = (t0 + 1 < t1) ? LOADREC(t0 + 1) : recA;
    bf16x8 u0, u1, v0, v1;
    ISSUE_UV(recA, u0, u1, v0, v1);

    for (int t = t0; t < t1; ++t){
        uint2 recC = LOADREC(t + 2 < t1 ? t + 2 : t1 - 1);
        bf16x8 nu0, nu1, nv0, nv1;
        ISSUE_UV(recB, nu0, nu1, nv0, nv1);     // next tile's gathers in flight

        int rn_raw = (int)(recA.x & 0xFFFFu);
        int rn = (rn_raw == 0xFFFF) ? -1 : rn_raw;
        float ef0 = bf2f((short)(recA.y & 0xFFFFu));
        float ef1 = bf2f((short)(recA.y >> 16));

        float xl[8], xh[8];
        #pragma unroll
        for (int j = 0; j < 8; ++j){
            float hA = fmaf(ef1, e1l[j], ef0 * e0l[j]);
            float hB = fmaf(ef1, e1h[j], ef0 * e0h[j]);
            xl[j] = fmaxf(hA + bf2f(u0[j]) + bf2f(v0[j]), 0.f);
            xh[j] = fmaxf(hB + bf2f(u1[j]) + bf2f(v1[j]), 0.f);
        }
        bf16x8 a0, a1;
        PACK8(a0, xl);
        PACK8(a1, xh);

        f32x4 m[4];
        #pragma unroll
        for (int f = 0; f < 4; ++f){ m[f][0]=bias2[f]; m[f][1]=bias2[f]; m[f][2]=bias2[f]; m[f][3]=bias2[f]; }
        #pragma unroll
        for (int f = 0; f < 4; ++f) m[f] = MFMA16(a0, bW2[0][f], m[f]);
        #pragma unroll
        for (int f = 0; f < 4; ++f) m[f] = MFMA16(a1, bW2[1][f], m[f]);

        // C-layout messages -> LDS so lane = feature
        #pragma unroll
        for (int f = 0; f < 4; ++f)
            #pragma unroll
            for (int r = 0; r < 4; ++r)
                myMsg[(quad * 4 + r) * 68 + f * 16 + l15] = m[f][r];

        // segmented reduction over 16 ROW-SORTED edges -> sparse global atomics
        float accv = 0.f;
        int cur = __shfl(rn, 0);
        #pragma unroll
        for (int j = 0; j < 16; ++j){
            int rj = __shfl(rn, j);
            if (rj != cur){
                if (cur >= 0) atomicAdd(agg + (size_t)cur * 64 + l, accv);
                accv = 0.f; cur = rj;
            }
            accv += myMsg[j * 68 + l];
        }
        if (cur >= 0) atomicAdd(agg + (size_t)cur * 64 + l, accv);

        recA = recB; recB = recC;
        u0 = nu0; u1 = nu1; v0 = nv0; v1 = nv1;
    }
}

// -- update: h = relu(LN(agg + h@SW + SB)); zero agg; emit U,V for next layer -
__global__ __launch_bounds__(256) void update_kernel(
    u16* __restrict__ hbf, float* __restrict__ agg,
    const float* __restrict__ SW, const float* __restrict__ SB,
    const float* __restrict__ LG, const float* __restrict__ LB,
    const float* __restrict__ cW1, const float* __restrict__ cB1,  // next layer (may be null)
    u16* __restrict__ Ubf, u16* __restrict__ Vbf, int N)
{
    __shared__ u16 sH[64 * 72];
    const int tid = threadIdx.x;
    const int w = tid >> 6, l = tid & 63, l15 = l & 15, quad = l >> 4;

    bf16x8 bW[2][4];
    #pragma unroll
    for (int kk = 0; kk < 2; ++kk)
        #pragma unroll
        for (int f = 0; f < 4; ++f)
            bW[kk][f] = load_bfrag(SW, 64, f * 16 + l15, kk * 32 + quad * 8);
    float sb[4], lg[4], lb[4];
    #pragma unroll
    for (int f = 0; f < 4; ++f){
        int n = f * 16 + l15;
        sb[f] = SB[n]; lg[f] = LG[n]; lb[f] = LB[n];
    }

    const int nbase = blockIdx.x * 64 + w * 16;
    int na = nbase + l15; if (na > N - 1) na = N - 1;
    const u16* pa = hbf + (size_t)na * 64 + quad * 8;
    bf16x8 h0 = *(const bf16x8*)pa;
    bf16x8 h1 = *(const bf16x8*)(pa + 32);

    f32x4 acc[4] = {};
    #pragma unroll
    for (int f = 0; f < 4; ++f) acc[f] = MFMA16(h0, bW[0][f], acc[f]);
    #pragma unroll
    for (int f = 0; f < 4; ++f) acc[f] = MFMA16(h1, bW[1][f], acc[f]);

    float vals[4][4];
    #pragma unroll
    for (int r = 0; r < 4; ++r){
        int node = nbase + quad * 4 + r; if (node > N - 1) node = N - 1;
        #pragma unroll
        for (int f = 0; f < 4; ++f)
            vals[f][r] = acc[f][r] + sb[f] + agg[(size_t)node * 64 + f * 16 + l15];
    }

    #pragma unroll
    for (int r = 0; r < 4; ++r){
        float s  = vals[0][r] + vals[1][r] + vals[2][r] + vals[3][r];
        float sq = vals[0][r]*vals[0][r] + vals[1][r]*vals[1][r]
                 + vals[2][r]*vals[2][r] + vals[3][r]*vals[3][r];
        #pragma unroll
        for (int msk = 1; msk < 16; msk <<= 1){
            s  += __shfl_xor(s,  msk);
            sq += __shfl_xor(sq, msk);
        }
        float mean = s * (1.f / 64.f);
        float var  = sq * (1.f / 64.f) - mean * mean;
        float rstd = rsqrtf(var + 1e-5f);
        int node = nbase + quad * 4 + r;
        #pragma unroll
        for (int f = 0; f < 4; ++f){
            float hv = (vals[f][r] - mean) * rstd * lg[f] + lb[f];
            hv = hv > 0.f ? hv : 0.f;
            u16 hb = f2bf(hv);
            sH[(w * 16 + quad * 4 + r) * 72 + f * 16 + l15] = hb;
            if (node < N){
                hbf[(size_t)node * 64 + f * 16 + l15] = hb;
                agg[(size_t)node * 64 + f * 16 + l15] = 0.f;   // ready for next layer
            }
        }
    }

    if (cW1){
        bf16x8 bA[2][4], bB[2][4];
        #pragma unroll
        for (int kk = 0; kk < 2; ++kk)
            #pragma unroll
            for (int f = 0; f < 4; ++f){
                int n = f * 16 + l15, k0 = kk * 32 + quad * 8;
                bA[kk][f] = load_bfrag(cW1,           64, n, k0);
                bB[kk][f] = load_bfrag(cW1 + 64 * 64, 64, n, k0);
            }
        float b1n[4];
        #pragma unroll
        for (int f = 0; f < 4; ++f) b1n[f] = cB1[f * 16 + l15];

        bf16x8 a0 = *(const bf16x8*)&sH[(w * 16 + l15) * 72 + quad * 8];
        bf16x8 a1 = *(const bf16x8*)&sH[(w * 16 + l15) * 72 + 32 + quad * 8];

        f32x4 ua[4], va[4];
        #pragma unroll
        for (int f = 0; f < 4; ++f){
            ua[f][0]=b1n[f]; ua[f][1]=b1n[f]; ua[f][2]=b1n[f]; ua[f][3]=b1n[f];
            va[f][0]=0.f; va[f][1]=0.f; va[f][2]=0.f; va[f][3]=0.f;
        }
        #pragma unroll
        for (int f = 0; f < 4; ++f){ ua[f] = MFMA16(a0, bA[0][f], ua[f]); va[f] = MFMA16(a0, bB[0][f], va[f]); }
        #pragma unroll
        for (int f = 0; f < 4; ++f){ ua[f] = MFMA16(a1, bA[1][f], ua[f]); va[f] = MFMA16(a1, bB[1][f], va[f]); }

        #pragma unroll
        for (int r = 0; r < 4; ++r){
            int node = nbase + quad * 4 + r;
            if (node < N){
                #pragma unroll
                for (int f = 0; f < 4; ++f){
                    Ubf[(size_t)node * 64 + f * 16 + l15] = f2bf(ua[f][r]);
                    Vbf[(size_t)node * 64 + f * 16 + l15] = f2bf(va[f][r]);
                }
            }
        }
    }
}

// ---------------- head: out = relu(h@W1+b1)@W2 + b2  [N][8] f32 --------------
__global__ __launch_bounds__(256) void head_kernel(
    const u16* __restrict__ hbf,
    const float* __restrict__ W1, const float* __restrict__ B1,
    const float* __restrict__ W2, const float* __restrict__ B2,
    float* __restrict__ out, int N)
{
    __shared__ u16 sT[64 * 72];
    const int tid = threadIdx.x;
    const int w = tid >> 6, l = tid & 63, l15 = l & 15, quad = l >> 4;

    bf16x8 bW1[2][4];
    #pragma unroll
    for (int kk = 0; kk < 2; ++kk)
        #pragma unroll
        for (int f = 0; f < 4; ++f)
            bW1[kk][f] = load_bfrag(W1, 64, f * 16 + l15, kk * 32 + quad * 8);
    float b1v[4];
    #pragma unroll
    for (int f = 0; f < 4; ++f) b1v[f] = B1[f * 16 + l15];

    bf16x8 bW2[2];
    #pragma unroll
    for (int kk = 0; kk < 2; ++kk)
        #pragma unroll
        for (int j = 0; j < 8; ++j){
            int k = kk * 32 + quad * 8 + j;
            bW2[kk][j] = (l15 < 8) ? (short)f2bf(W2[k * 8 + l15]) : (short)0;
        }
    float b2v = (l15 < 8) ? B2[l15] : 0.f;

    const int nbase = blockIdx.x * 64 + w * 16;
    int na = nbase + l15; if (na > N - 1) na = N - 1;
    const u16* pa = hbf + (size_t)na * 64 + quad * 8;
    bf16x8 a0 = *(const bf16x8*)pa;
    bf16x8 a1 = *(const bf16x8*)(pa + 32);

    f32x4 acc[4];
    #pragma unroll
    for (int f = 0; f < 4; ++f){ acc[f][0]=b1v[f]; acc[f][1]=b1v[f]; acc[f][2]=b1v[f]; acc[f][3]=b1v[f]; }
    #pragma unroll
    for (int f = 0; f < 4; ++f) acc[f] = MFMA16(a0, bW1[0][f], acc[f]);
    #pragma unroll
    for (int f = 0; f < 4; ++f) acc[f] = MFMA16(a1, bW1[1][f], acc[f]);

    u16* myT = sT + (w * 16) * 72;
    #pragma unroll
    for (int f = 0; f < 4; ++f)
        #pragma unroll
        for (int r = 0; r < 4; ++r){
            float v = acc[f][r] > 0.f ? acc[f][r] : 0.f;
            myT[(quad * 4 + r) * 72 + f * 16 + l15] = f2bf(v);
        }

    f32x4 o = { b2v, b2v, b2v, b2v };
    #pragma unroll
    for (int kk = 0; kk < 2; ++kk){
        bf16x8 a = *(const bf16x8*)&myT[l15 * 72 + kk * 32 + quad * 8];
        o = MFMA16(a, bW2[kk], o);
    }
    #pragma unroll
    for (int r = 0; r < 4; ++r){
        int node = nbase + quad * 4 + r;
        if (node < N && l15 < 8)
            out[(size_t)node * 8 + l15] = o[r];
    }
}

extern "C" void kernel_launch(void* const* d_in, const int* in_sizes, int n_in,
                              void* d_out, int out_size, void* d_ws, size_t ws_size,
                              hipStream_t stream)
{
    const float* X      = (const float*)d_in[0];
    const int*   EI     = (const int*)d_in[1];
    const float* EF     = (const float*)d_in[2];
    const float* encW1  = (const float*)d_in[4];
    const float* encB1  = (const float*)d_in[5];
    const float* encW2  = (const float*)d_in[6];
    const float* encB2  = (const float*)d_in[7];
    const float* convW1 = (const float*)d_in[8];
    const float* convB1 = (const float*)d_in[9];
    const float* convW2 = (const float*)d_in[10];
    const float* convB2 = (const float*)d_in[11];
    const float* skipW  = (const float*)d_in[12];
    const float* skipB  = (const float*)d_in[13];
    const float* lnG    = (const float*)d_in[14];
    const float* lnB    = (const float*)d_in[15];
    const float* headW1 = (const float*)d_in[16];
    const float* headB1 = (const float*)d_in[17];
    const float* headW2 = (const float*)d_in[18];
    const float* headB2 = (const float*)d_in[19];

    const int N = in_sizes[0] / 3;      // NOTE: packing assumes N < 65535
    const int E = in_sizes[1] / 2;
    const int L = in_sizes[8] / (130 * 64);
    const int* rows = EI;
    const int* cols = EI + E;

    const int NB = (N + 63) / 64;       // buckets = 64-row tiles (<= 1024)

    auto align256 = [](size_t x){ return (x + 255) & ~(size_t)255; };
    char* p = (char*)d_ws;
    u16* hbf = (u16*)p;             p += align256((size_t)N * 64 * 2);
    u16* Ubf = (u16*)p;             p += align256((size_t)N * 64 * 2);
    u16* Vbf = (u16*)p;             p += align256((size_t)N * 64 * 2);
    float* agg = (float*)p;         p += align256((size_t)N * 64 * 4);
    uint2* erec = (uint2*)p;        p += align256((size_t)E * 8);
    int* countsB = (int*)p;         p += align256(1024 * 4);
    int* offsets = (int*)p;         p += align256(1032 * 4);
    int* cursorB = (int*)p;         p += align256(1024 * 4);

    // ---- build bucket-binned, row-sorted packed edge records ----
    hipMemsetAsync(countsB, 0, (size_t)NB * sizeof(int), stream);
    countB_kernel<<<256, 256, 0, stream>>>(rows, countsB, E, NB);
    scanB_kernel<<<1, 1024, 0, stream>>>(countsB, offsets, cursorB, NB);
    binpack_kernel<<<(E + CHUNK - 1) / CHUNK, 1024, 0, stream>>>(rows, cols, EF, cursorB, erec, E);
    rowsort_kernel<<<NB, 256, 0, stream>>>(erec, offsets);

    hipMemsetAsync(agg, 0, (size_t)N * 64 * sizeof(float), stream);
    enc_kernel<<<NB, 256, 0, stream>>>(X, encW1, encB1, encW2, encB2,
                                       convW1, convB1, hbf, Ubf, Vbf, N);

    for (int li = 0; li < L; ++li){
        msg_kernel<<<NB * 2, 256, 0, stream>>>(Ubf, Vbf, erec, offsets,
            convW1 + (size_t)li * 130 * 64,
            convW2 + (size_t)li * 64 * 64, convB2 + li * 64,
            agg, N);
        const float* w1n = (li + 1 < L) ? convW1 + (size_t)(li + 1) * 130 * 64 : nullptr;
        const float* b1n = (li + 1 < L) ? convB1 + (li + 1) * 64 : nullptr;
        update_kernel<<<NB, 256, 0, stream>>>(hbf, agg,
            skipW + (size_t)li * 64 * 64, skipB + li * 64,
            lnG + li * 64, lnB + li * 64, w1n, b1n, Ubf, Vbf, N);
    }
    head_kernel<<<NB, 256, 0, stream>>>(hbf, headW1, headB1, headW2, headB2,
                                        (float*)d_out, N);
}

// Round 8
// 327.063 us; speedup vs baseline: 4.9119x; 1.0979x over previous
//
#include <hip/hip_runtime.h>

typedef unsigned short u16;
typedef __attribute__((ext_vector_type(8))) short bf16x8;
typedef __attribute__((ext_vector_type(4))) float f32x4;

#define MFMA16(a,b,c) __builtin_amdgcn_mfma_f32_16x16x32_bf16((a),(b),(c),0,0,0)

static __device__ __forceinline__ u16 f2bf(float x){
    unsigned int u = __float_as_uint(x);
    u += 0x7FFFu + ((u >> 16) & 1u);
    return (u16)(u >> 16);
}
static __device__ __forceinline__ float bf2f(short s){
    return __uint_as_float(((unsigned int)(u16)s) << 16);
}

static __device__ __forceinline__ bf16x8 load_bfrag(const float* __restrict__ W, int ldn, int n, int k0){
    bf16x8 r;
    #pragma unroll
    for (int j = 0; j < 8; ++j) r[j] = (short)f2bf(W[(k0 + j) * ldn + n]);
    return r;
}

// ---------------- encoder: h = relu(x@W1+b1)@W2 + b2 ; emit h, U0, V0 --------
__global__ __launch_bounds__(256) void enc_kernel(
    const float* __restrict__ X, const float* __restrict__ W1, const float* __restrict__ B1,
    const float* __restrict__ W2, const float* __restrict__ B2,
    const float* __restrict__ cW1, const float* __restrict__ cB1,   // conv layer-0
    u16* __restrict__ hbf, u16* __restrict__ Ubf, u16* __restrict__ Vbf, int N)
{
    __shared__ u16 sHid[64 * 136];
    __shared__ u16 sH[64 * 72];
    const int tid = threadIdx.x;
    const int w = tid >> 6, l = tid & 63, l15 = l & 15, quad = l >> 4;

    bf16x8 bW[4][4];
    #pragma unroll
    for (int ks = 0; ks < 4; ++ks)
        #pragma unroll
        for (int f = 0; f < 4; ++f)
            bW[ks][f] = load_bfrag(W2, 64, f * 16 + l15, ks * 32 + quad * 8);
    float b2v[4];
    #pragma unroll
    for (int f = 0; f < 4; ++f) b2v[f] = B2[f * 16 + l15];

    const int nbase = blockIdx.x * 64 + w * 16;

    {
        int e = l >> 2;
        int node = nbase + e; if (node > N - 1) node = N - 1;
        float x0 = X[node * 3], x1 = X[node * 3 + 1], x2 = X[node * 3 + 2];
        int k0 = (l & 3) * 32;
        u16* dst = sHid + (w * 16 + e) * 136 + k0;
        #pragma unroll
        for (int j = 0; j < 32; ++j){
            int k = k0 + j;
            float hv = x0 * W1[k] + x1 * W1[128 + k] + x2 * W1[256 + k] + B1[k];
            dst[j] = f2bf(hv > 0.f ? hv : 0.f);
        }
    }

    f32x4 acc[4];
    #pragma unroll
    for (int f = 0; f < 4; ++f){ acc[f][0]=b2v[f]; acc[f][1]=b2v[f]; acc[f][2]=b2v[f]; acc[f][3]=b2v[f]; }
    #pragma unroll
    for (int ks = 0; ks < 4; ++ks){
        bf16x8 a = *(const bf16x8*)&sHid[(w * 16 + l15) * 136 + ks * 32 + quad * 8];
        #pragma unroll
        for (int f = 0; f < 4; ++f) acc[f] = MFMA16(a, bW[ks][f], acc[f]);
    }
    #pragma unroll
    for (int r = 0; r < 4; ++r){
        int node = nbase + quad * 4 + r;
        #pragma unroll
        for (int f = 0; f < 4; ++f){
            u16 hb = f2bf(acc[f][r]);
            sH[(w * 16 + quad * 4 + r) * 72 + f * 16 + l15] = hb;
            if (node < N) hbf[(size_t)node * 64 + f * 16 + l15] = hb;
        }
    }

    // U = h@cW1a + cB1 ; V = h@cW1b   (same-wave LDS write->read, no barrier)
    bf16x8 bA[2][4], bB[2][4];
    #pragma unroll
    for (int kk = 0; kk < 2; ++kk)
        #pragma unroll
        for (int f = 0; f < 4; ++f){
            int n = f * 16 + l15, k0 = kk * 32 + quad * 8;
            bA[kk][f] = load_bfrag(cW1,           64, n, k0);
            bB[kk][f] = load_bfrag(cW1 + 64 * 64, 64, n, k0);
        }
    float b1n[4];
    #pragma unroll
    for (int f = 0; f < 4; ++f) b1n[f] = cB1[f * 16 + l15];

    bf16x8 a0 = *(const bf16x8*)&sH[(w * 16 + l15) * 72 + quad * 8];
    bf16x8 a1 = *(const bf16x8*)&sH[(w * 16 + l15) * 72 + 32 + quad * 8];

    f32x4 ua[4], va[4];
    #pragma unroll
    for (int f = 0; f < 4; ++f){
        ua[f][0]=b1n[f]; ua[f][1]=b1n[f]; ua[f][2]=b1n[f]; ua[f][3]=b1n[f];
        va[f][0]=0.f; va[f][1]=0.f; va[f][2]=0.f; va[f][3]=0.f;
    }
    #pragma unroll
    for (int f = 0; f < 4; ++f){ ua[f] = MFMA16(a0, bA[0][f], ua[f]); va[f] = MFMA16(a0, bB[0][f], va[f]); }
    #pragma unroll
    for (int f = 0; f < 4; ++f){ ua[f] = MFMA16(a1, bA[1][f], ua[f]); va[f] = MFMA16(a1, bB[1][f], va[f]); }

    #pragma unroll
    for (int r = 0; r < 4; ++r){
        int node = nbase + quad * 4 + r;
        if (node < N){
            #pragma unroll
            for (int f = 0; f < 4; ++f){
                Ubf[(size_t)node * 64 + f * 16 + l15] = f2bf(ua[f][r]);
                Vbf[(size_t)node * 64 + f * 16 + l15] = f2bf(va[f][r]);
            }
        }
    }
}

// ---------------- bucket binning build (bucket = 64 dest rows) ---------------
__global__ __launch_bounds__(256) void countB_kernel(const int* __restrict__ rows,
                                                     int* __restrict__ countsB, int E, int NB){
    __shared__ int c[1024];
    for (int i = threadIdx.x; i < NB; i += 256) c[i] = 0;
    __syncthreads();
    for (int i = blockIdx.x * 256 + threadIdx.x; i < E; i += gridDim.x * 256)
        atomicAdd(&c[rows[i] >> 6], 1);
    __syncthreads();
    for (int i = threadIdx.x; i < NB; i += 256){
        int v = c[i];
        if (v) atomicAdd(&countsB[i], v);
    }
}

__global__ __launch_bounds__(1024) void scanB_kernel(const int* __restrict__ countsB,
                                                     int* __restrict__ offsets,
                                                     int* __restrict__ cursorB, int NB){
    __shared__ int sc[1024];
    const int tid = threadIdx.x;
    int x = (tid < NB) ? countsB[tid] : 0;
    sc[tid] = x;
    __syncthreads();
    for (int d = 1; d < 1024; d <<= 1){
        int v = (tid >= d) ? sc[tid - d] : 0;
        __syncthreads();
        sc[tid] += v;
        __syncthreads();
    }
    int excl = sc[tid] - x;
    if (tid < NB){ offsets[tid] = excl; cursorB[tid] = excl; }
    if (tid == NB - 1) offsets[NB] = sc[tid];
}

#define CHUNK 8192

__global__ __launch_bounds__(1024) void binpack_kernel(
    const int* __restrict__ rows, const int* __restrict__ cols,
    const float* __restrict__ EF, int* __restrict__ cursorB,
    uint2* __restrict__ erec, int E)
{
    __shared__ u16 sRow[CHUNK];
    __shared__ u16 sPerm[CHUNK];
    __shared__ int cntA[1024], cntE[1024], cntC[1024], baseB[1024], sc[1024];
    const int tid = threadIdx.x;
    const int cbase = blockIdx.x * CHUNK;
    int C = E - cbase; if (C > CHUNK) C = CHUNK;
    if (C <= 0) return;

    cntA[tid] = 0;
    __syncthreads();
    for (int k = tid; k < C; k += 1024){
        int r = rows[cbase + k];
        sRow[k] = (u16)r;
        atomicAdd(&cntA[r >> 6], 1);
    }
    __syncthreads();
    sc[tid] = cntA[tid];
    __syncthreads();
    for (int d = 1; d < 1024; d <<= 1){
        int v = (tid >= d) ? sc[tid - d] : 0;
        __syncthreads();
        sc[tid] += v;
        __syncthreads();
    }
    int excl = sc[tid] - cntA[tid];
    cntE[tid] = excl;
    cntC[tid] = excl;
    if (cntA[tid] > 0) baseB[tid] = atomicAdd(&cursorB[tid], cntA[tid]);
    __syncthreads();
    for (int k = tid; k < C; k += 1024){
        int b = sRow[k] >> 6;
        int p = atomicAdd(&cntC[b], 1);
        sPerm[p] = (u16)k;
    }
    __syncthreads();
    for (int p = tid; p < C; p += 1024){
        int k = sPerm[p];
        int i = cbase + k;
        int r = sRow[k];
        int b = r >> 6;
        float2 ef = *(const float2*)&EF[2 * i];
        uint2 v;
        v.x = (unsigned)r | ((unsigned)cols[i] << 16);
        v.y = (unsigned)f2bf(ef.x) | ((unsigned)f2bf(ef.y) << 16);
        erec[baseB[b] + (p - cntE[b])] = v;
    }
}

// issue U/V gathers for a record (loads start here; waited at first use)
#define ISSUE_UV(recv, U0, U1, V0, V1) do {                                  \
    int rr_ = (int)((recv).x & 0xFFFFu); if (rr_ == 0xFFFF) rr_ = 0;         \
    int cc_ = (int)((recv).x >> 16);                                         \
    const u16* pu_ = Ubf + (size_t)rr_ * 64 + quad * 8;                      \
    const u16* pv_ = Vbf + (size_t)cc_ * 64 + quad * 8;                      \
    U0 = *(const bf16x8*)(pu_);                                              \
    U1 = *(const bf16x8*)(pu_ + 32);                                         \
    V0 = *(const bf16x8*)(pv_);                                              \
    V1 = *(const bf16x8*)(pv_ + 32);                                         \
} while (0)

// pack 2 floats -> 1 dword of 2 bf16 (RTNE), src0 -> low half
static __device__ __forceinline__ unsigned cvtpk(float a, float b){
    unsigned d;
    asm("v_cvt_pk_bf16_f32 %0, %1, %2" : "=v"(d) : "v"(a), "v"(b));
    return d;
}
#define PACK8(dst, x) do {                                                   \
    union { bf16x8 v; unsigned int d[4]; } _u;                               \
    _u.d[0] = cvtpk(x[0], x[1]); _u.d[1] = cvtpk(x[2], x[3]);                \
    _u.d[2] = cvtpk(x[4], x[5]); _u.d[3] = cvtpk(x[6], x[7]);                \
    dst = _u.v;                                                              \
} while (0)

// ==== fused layer: messages + S-matrix MFMA scatter (reg agg) + update =======
// one block per bucket (64 dest rows); no global atomics, agg never in memory.
__global__ __launch_bounds__(256, 3) void fused_kernel(
    const u16* __restrict__ Ubf, const u16* __restrict__ Vbf,   // this layer U/V
    const uint2* __restrict__ erec, const int* __restrict__ offsets,
    const float* __restrict__ W1,   // conv W1 [130][64] (ef rows 128,129)
    const float* __restrict__ W2, const float* __restrict__ B2,
    u16* __restrict__ hbf,
    const float* __restrict__ SW, const float* __restrict__ SB,
    const float* __restrict__ LG, const float* __restrict__ LB,
    const float* __restrict__ cW1, const float* __restrict__ cB1, // next layer (may be null)
    u16* __restrict__ Un, u16* __restrict__ Vn,                   // next layer U/V out
    int N)
{
    __shared__ u16 sMsgT[2][64 * 72];   // feat-major bf16 messages, dbuf (stride 72 u16 = 144B)
    __shared__ u16 sRowT[2][64];        // relative row per edge slot (0xFFFF pad)
    __shared__ u16 sH[64 * 72];
    const int tid = threadIdx.x;
    const int w = tid >> 6, l = tid & 63, l15 = l & 15, quad = l >> 4;
    const int w16 = w * 16;

    // message-phase weights
    bf16x8 bW2[2][4];
    #pragma unroll
    for (int kk = 0; kk < 2; ++kk)
        #pragma unroll
        for (int f = 0; f < 4; ++f)
            bW2[kk][f] = load_bfrag(W2, 64, f * 16 + l15, kk * 32 + quad * 8);
    float bias2[4];
    #pragma unroll
    for (int f = 0; f < 4; ++f) bias2[f] = B2[f * 16 + l15];

    const float* Wc0 = W1 + 128 * 64;
    const float* Wc1 = W1 + 129 * 64;
    float e0l[8], e0h[8], e1l[8], e1h[8];
    #pragma unroll
    for (int j = 0; j < 8; ++j){
        int kl = quad * 8 + j;
        e0l[j] = Wc0[kl];       e0h[j] = Wc0[32 + kl];
        e1l[j] = Wc1[kl];       e1h[j] = Wc1[32 + kl];
    }

    const int b = blockIdx.x;
    const int start = offsets[b], end = offsets[b + 1];
    const int nt = (end - start + 63) >> 6;
    const int tgtrow = w16 + l15;       // this lane's owned relative row

    f32x4 aggC[4] = {};                  // wave's 16 rows x 64 feats, C layout

    auto LOADREC = [&](int t) -> uint2 {
        int e = start + t * 64 + w16 + l15;
        if (e < end) return erec[e];
        uint2 s; s.x = 0x0000FFFFu; s.y = 0u; return s;
    };

    if (nt > 0){
        uint2 recA = LOADREC(0);
        uint2 recB = (nt > 1) ? LOADREC(1) : recA;
        bf16x8 u0, u1, v0, v1;
        ISSUE_UV(recA, u0, u1, v0, v1);

        for (int t = 0; t < nt; ++t){
            uint2 recC = LOADREC(t + 2 < nt ? t + 2 : nt - 1);
            bf16x8 nu0, nu1, nv0, nv1;
            ISSUE_UV(recB, nu0, nu1, nv0, nv1);   // next tile's gathers in flight

            int rn_raw = (int)(recA.x & 0xFFFFu);
            float ef0 = bf2f((short)(recA.y & 0xFFFFu));
            float ef1 = bf2f((short)(recA.y >> 16));

            float xl[8], xh[8];
            #pragma unroll
            for (int j = 0; j < 8; ++j){
                float hA = fmaf(ef1, e1l[j], ef0 * e0l[j]);
                float hB = fmaf(ef1, e1h[j], ef0 * e0h[j]);
                xl[j] = fmaxf(hA + bf2f(u0[j]) + bf2f(v0[j]), 0.f);
                xh[j] = fmaxf(hB + bf2f(u1[j]) + bf2f(v1[j]), 0.f);
            }
            bf16x8 a0, a1;
            PACK8(a0, xl);
            PACK8(a1, xh);

            f32x4 m[4];
            #pragma unroll
            for (int f = 0; f < 4; ++f){ m[f][0]=bias2[f]; m[f][1]=bias2[f]; m[f][2]=bias2[f]; m[f][3]=bias2[f]; }
            #pragma unroll
            for (int f = 0; f < 4; ++f) m[f] = MFMA16(a0, bW2[0][f], m[f]);
            #pragma unroll
            for (int f = 0; f < 4; ++f) m[f] = MFMA16(a1, bW2[1][f], m[f]);

            // transposed (feat-major) bf16 messages -> LDS
            const int buf = t & 1;
            #pragma unroll
            for (int f = 0; f < 4; ++f){
                uint2 wv;
                wv.x = cvtpk(m[f][0], m[f][1]);
                wv.y = cvtpk(m[f][2], m[f][3]);
                *(uint2*)&sMsgT[buf][(f * 16 + l15) * 72 + w16 + quad * 4] = wv;
            }
            if (quad == 0)
                sRowT[buf][w16 + l15] = (rn_raw == 0xFFFF) ? (u16)0xFFFF : (u16)(rn_raw & 63);

            __syncthreads();

            // scatter: aggC += S (onehot rows) x M  (2 e-chunks x 4 f-chunks)
            #pragma unroll
            for (int c = 0; c < 2; ++c){
                union { bf16x8 v; unsigned d[4]; } sfr;
                union { uint4 q; unsigned d[4]; } rv;
                rv.q = *(const uint4*)&sRowT[buf][c * 32 + quad * 8];
                #pragma unroll
                for (int k = 0; k < 4; ++k){
                    unsigned d = rv.d[k];
                    unsigned lo = d & 0xFFFFu, hi = d >> 16;
                    sfr.d[k] = (lo == (unsigned)tgtrow ? 0x3F80u : 0u)
                             | (hi == (unsigned)tgtrow ? 0x3F800000u : 0u);
                }
                #pragma unroll
                for (int f = 0; f < 4; ++f){
                    bf16x8 mb = *(const bf16x8*)&sMsgT[buf][(f * 16 + l15) * 72 + c * 32 + quad * 8];
                    aggC[f] = MFMA16(sfr.v, mb, aggC[f]);
                }
            }
            // no 2nd barrier: next tile writes the other buffer

            recA = recB; recB = recC;
            u0 = nu0; u1 = nu1; v0 = nv0; v1 = nv1;
        }
    }

    // ---------------- fused update: h = relu(LN(aggC + h@SW + SB)) -----------
    bf16x8 bW[2][4];
    #pragma unroll
    for (int kk = 0; kk < 2; ++kk)
        #pragma unroll
        for (int f = 0; f < 4; ++f)
            bW[kk][f] = load_bfrag(SW, 64, f * 16 + l15, kk * 32 + quad * 8);
    float sb[4], lg[4], lb[4];
    #pragma unroll
    for (int f = 0; f < 4; ++f){
        int n = f * 16 + l15;
        sb[f] = SB[n]; lg[f] = LG[n]; lb[f] = LB[n];
    }

    const int nbase = b * 64 + w16;
    int na = nbase + l15; if (na > N - 1) na = N - 1;
    const u16* pa = hbf + (size_t)na * 64 + quad * 8;
    bf16x8 h0 = *(const bf16x8*)pa;
    bf16x8 h1 = *(const bf16x8*)(pa + 32);

    f32x4 acc[4] = {};
    #pragma unroll
    for (int f = 0; f < 4; ++f) acc[f] = MFMA16(h0, bW[0][f], acc[f]);
    #pragma unroll
    for (int f = 0; f < 4; ++f) acc[f] = MFMA16(h1, bW[1][f], acc[f]);

    float vals[4][4];
    #pragma unroll
    for (int r = 0; r < 4; ++r)
        #pragma unroll
        for (int f = 0; f < 4; ++f)
            vals[f][r] = acc[f][r] + sb[f] + aggC[f][r];

    #pragma unroll
    for (int r = 0; r < 4; ++r){
        float s  = vals[0][r] + vals[1][r] + vals[2][r] + vals[3][r];
        float sq = vals[0][r]*vals[0][r] + vals[1][r]*vals[1][r]
                 + vals[2][r]*vals[2][r] + vals[3][r]*vals[3][r];
        #pragma unroll
        for (int msk = 1; msk < 16; msk <<= 1){
            s  += __shfl_xor(s,  msk);
            sq += __shfl_xor(sq, msk);
        }
        float mean = s * (1.f / 64.f);
        float var  = sq * (1.f / 64.f) - mean * mean;
        float rstd = rsqrtf(var + 1e-5f);
        int node = nbase + quad * 4 + r;
        #pragma unroll
        for (int f = 0; f < 4; ++f){
            float hv = (vals[f][r] - mean) * rstd * lg[f] + lb[f];
            hv = hv > 0.f ? hv : 0.f;
            u16 hb = f2bf(hv);
            sH[(w16 + quad * 4 + r) * 72 + f * 16 + l15] = hb;
            if (node < N) hbf[(size_t)node * 64 + f * 16 + l15] = hb;
        }
    }

    if (cW1){
        bf16x8 bA[2][4], bB[2][4];
        #pragma unroll
        for (int kk = 0; kk < 2; ++kk)
            #pragma unroll
            for (int f = 0; f < 4; ++f){
                int n = f * 16 + l15, k0 = kk * 32 + quad * 8;
                bA[kk][f] = load_bfrag(cW1,           64, n, k0);
                bB[kk][f] = load_bfrag(cW1 + 64 * 64, 64, n, k0);
            }
        float b1n[4];
        #pragma unroll
        for (int f = 0; f < 4; ++f) b1n[f] = cB1[f * 16 + l15];

        bf16x8 a0 = *(const bf16x8*)&sH[(w16 + l15) * 72 + quad * 8];
        bf16x8 a1 = *(const bf16x8*)&sH[(w16 + l15) * 72 + 32 + quad * 8];

        f32x4 ua[4], va[4];
        #pragma unroll
        for (int f = 0; f < 4; ++f){
            ua[f][0]=b1n[f]; ua[f][1]=b1n[f]; ua[f][2]=b1n[f]; ua[f][3]=b1n[f];
            va[f][0]=0.f; va[f][1]=0.f; va[f][2]=0.f; va[f][3]=0.f;
        }
        #pragma unroll
        for (int f = 0; f < 4; ++f){ ua[f] = MFMA16(a0, bA[0][f], ua[f]); va[f] = MFMA16(a0, bB[0][f], va[f]); }
        #pragma unroll
        for (int f = 0; f < 4; ++f){ ua[f] = MFMA16(a1, bA[1][f], ua[f]); va[f] = MFMA16(a1, bB[1][f], va[f]); }

        #pragma unroll
        for (int r = 0; r < 4; ++r){
            int node = nbase + quad * 4 + r;
            if (node < N){
                #pragma unroll
                for (int f = 0; f < 4; ++f){
                    Un[(size_t)node * 64 + f * 16 + l15] = f2bf(ua[f][r]);
                    Vn[(size_t)node * 64 + f * 16 + l15] = f2bf(va[f][r]);
                }
            }
        }
    }
}

// ---------------- head: out = relu(h@W1+b1)@W2 + b2  [N][8] f32 --------------
__global__ __launch_bounds__(256) void head_kernel(
    const u16* __restrict__ hbf,
    const float* __restrict__ W1, const float* __restrict__ B1,
    const float* __restrict__ W2, const float* __restrict__ B2,
    float* __restrict__ out, int N)
{
    __shared__ u16 sT[64 * 72];
    const int tid = threadIdx.x;
    const int w = tid >> 6, l = tid & 63, l15 = l & 15, quad = l >> 4;

    bf16x8 bW1[2][4];
    #pragma unroll
    for (int kk = 0; kk < 2; ++kk)
        #pragma unroll
        for (int f = 0; f < 4; ++f)
            bW1[kk][f] = load_bfrag(W1, 64, f * 16 + l15, kk * 32 + quad * 8);
    float b1v[4];
    #pragma unroll
    for (int f = 0; f < 4; ++f) b1v[f] = B1[f * 16 + l15];

    bf16x8 bW2[2];
    #pragma unroll
    for (int kk = 0; kk < 2; ++kk)
        #pragma unroll
        for (int j = 0; j < 8; ++j){
            int k = kk * 32 + quad * 8 + j;
            bW2[kk][j] = (l15 < 8) ? (short)f2bf(W2[k * 8 + l15]) : (short)0;
        }
    float b2v = (l15 < 8) ? B2[l15] : 0.f;

    const int nbase = blockIdx.x * 64 + w * 16;
    int na = nbase + l15; if (na > N - 1) na = N - 1;
    const u16* pa = hbf + (size_t)na * 64 + quad * 8;
    bf16x8 a0 = *(const bf16x8*)pa;
    bf16x8 a1 = *(const bf16x8*)(pa + 32);

    f32x4 acc[4];
    #pragma unroll
    for (int f = 0; f < 4; ++f){ acc[f][0]=b1v[f]; acc[f][1]=b1v[f]; acc[f][2]=b1v[f]; acc[f][3]=b1v[f]; }
    #pragma unroll
    for (int f = 0; f < 4; ++f) acc[f] = MFMA16(a0, bW1[0][f], acc[f]);
    #pragma unroll
    for (int f = 0; f < 4; ++f) acc[f] = MFMA16(a1, bW1[1][f], acc[f]);

    u16* myT = sT + (w * 16) * 72;
    #pragma unroll
    for (int f = 0; f < 4; ++f)
        #pragma unroll
        for (int r = 0; r < 4; ++r){
            float v = acc[f][r] > 0.f ? acc[f][r] : 0.f;
            myT[(quad * 4 + r) * 72 + f * 16 + l15] = f2bf(v);
        }

    f32x4 o = { b2v, b2v, b2v, b2v };
    #pragma unroll
    for (int kk = 0; kk < 2; ++kk){
        bf16x8 a = *(const bf16x8*)&myT[l15 * 72 + kk * 32 + quad * 8];
        o = MFMA16(a, bW2[kk], o);
    }
    #pragma unroll
    for (int r = 0; r < 4; ++r){
        int node = nbase + quad * 4 + r;
        if (node < N && l15 < 8)
            out[(size_t)node * 8 + l15] = o[r];
    }
}

extern "C" void kernel_launch(void* const* d_in, const int* in_sizes, int n_in,
                              void* d_out, int out_size, void* d_ws, size_t ws_size,
                              hipStream_t stream)
{
    const float* X      = (const float*)d_in[0];
    const int*   EI     = (const int*)d_in[1];
    const float* EF     = (const float*)d_in[2];
    const float* encW1  = (const float*)d_in[4];
    const float* encB1  = (const float*)d_in[5];
    const float* encW2  = (const float*)d_in[6];
    const float* encB2  = (const float*)d_in[7];
    const float* convW1 = (const float*)d_in[8];
    const float* convB1 = (const float*)d_in[9];
    const float* convW2 = (const float*)d_in[10];
    const float* convB2 = (const float*)d_in[11];
    const float* skipW  = (const float*)d_in[12];
    const float* skipB  = (const float*)d_in[13];
    const float* lnG    = (const float*)d_in[14];
    const float* lnB    = (const float*)d_in[15];
    const float* headW1 = (const float*)d_in[16];
    const float* headB1 = (const float*)d_in[17];
    const float* headW2 = (const float*)d_in[18];
    const float* headB2 = (const float*)d_in[19];

    const int N = in_sizes[0] / 3;      // NOTE: packing assumes N < 65535
    const int E = in_sizes[1] / 2;
    const int L = in_sizes[8] / (130 * 64);
    const int* rows = EI;
    const int* cols = EI + E;

    const int NB = (N + 63) / 64;       // buckets = 64-row tiles (<= 1024)

    auto align256 = [](size_t x){ return (x + 255) & ~(size_t)255; };
    char* p = (char*)d_ws;
    u16* hbf   = (u16*)p;           p += align256((size_t)N * 64 * 2);
    u16* Ubuf0 = (u16*)p;           p += align256((size_t)N * 64 * 2);
    u16* Vbuf0 = (u16*)p;           p += align256((size_t)N * 64 * 2);
    u16* Ubuf1 = (u16*)p;           p += align256((size_t)N * 64 * 2);
    u16* Vbuf1 = (u16*)p;           p += align256((size_t)N * 64 * 2);
    uint2* erec = (uint2*)p;        p += align256((size_t)E * 8);
    int* countsB = (int*)p;         p += align256(1024 * 4);
    int* offsets = (int*)p;         p += align256(1032 * 4);
    int* cursorB = (int*)p;         p += align256(1024 * 4);

    // ---- build bucket-binned packed edge records (once per call) ----
    hipMemsetAsync(countsB, 0, (size_t)NB * sizeof(int), stream);
    countB_kernel<<<256, 256, 0, stream>>>(rows, countsB, E, NB);
    scanB_kernel<<<1, 1024, 0, stream>>>(countsB, offsets, cursorB, NB);
    binpack_kernel<<<(E + CHUNK - 1) / CHUNK, 1024, 0, stream>>>(rows, cols, EF, cursorB, erec, E);

    enc_kernel<<<NB, 256, 0, stream>>>(X, encW1, encB1, encW2, encB2,
                                       convW1, convB1, hbf, Ubuf0, Vbuf0, N);

    u16* Ucur = Ubuf0; u16* Vcur = Vbuf0;
    u16* Ualt = Ubuf1; u16* Valt = Vbuf1;
    for (int li = 0; li < L; ++li){
        const float* w1n = (li + 1 < L) ? convW1 + (size_t)(li + 1) * 130 * 64 : nullptr;
        const float* b1n = (li + 1 < L) ? convB1 + (li + 1) * 64 : nullptr;
        fused_kernel<<<NB, 256, 0, stream>>>(Ucur, Vcur, erec, offsets,
            convW1 + (size_t)li * 130 * 64,
            convW2 + (size_t)li * 64 * 64, convB2 + li * 64,
            hbf,
            skipW + (size_t)li * 64 * 64, skipB + li * 64,
            lnG + li * 64, lnB + li * 64,
            w1n, b1n, Ualt, Valt, N);
        u16* t;
        t = Ucur; Ucur = Ualt; Ualt = t;
        t = Vcur; Vcur = Valt; Valt = t;
    }
    head_kernel<<<NB, 256, 0, stream>>>(hbf, headW1, headB1, headW2, headB2,
                                        (float*)d_out, N);
}